// Round 7
// baseline (1285.103 us; speedup 1.0000x reference)
//
#include <hip/hip_runtime.h>
#include <math.h>

#define CDIV(a,b) (((a)+(b)-1)/(b))

__device__ __forceinline__ float wred(float v){
  #pragma unroll
  for (int o = 32; o; o >>= 1) v += __shfl_xor(v, o, 64);
  return v;
}
__device__ __forceinline__ float leakyf(float x){ return x > 0.f ? x : 0.01f * x; }
__device__ __forceinline__ float sigmf(float x){ return 1.f / (1.f + expf(-x)); }
__device__ __forceinline__ float softplusf(float x){
  return fmaxf(x, 0.f) + log1pf(expf(-fabsf(x)));
}

// ---------------- degrees (both axes in one pass) ----------------
__global__ void k_deg2(const int* __restrict__ row, const int* __restrict__ col,
                       int* __restrict__ deg_row, int* __restrict__ deg_col, int E){
  int e = blockIdx.x * blockDim.x + threadIdx.x;
  if (e < E){
    atomicAdd(&deg_row[row[e]], 1);
    atomicAdd(&deg_col[col[e]], 1);
  }
}

// ---------------- exclusive scan of two N-arrays; block 1 also emits dinv ----------------
__global__ __launch_bounds__(1024) void k_scan2(const int* __restrict__ in0, int* __restrict__ out0,
                        const int* __restrict__ in1, int* __restrict__ out1,
                        float* __restrict__ dinv, int n){
  __shared__ int wincl[16];
  const int* in  = blockIdx.x ? in1 : in0;
  int* out       = blockIdx.x ? out1 : out0;
  int tid = threadIdx.x, lane = tid & 63, wv = tid >> 6;
  int carry = 0;
  for (int base = 0; base < n; base += 1024){
    int i = base + tid;
    int x = (i < n) ? in[i] : 0;
    int v = x;
    #pragma unroll
    for (int ofs = 1; ofs < 64; ofs <<= 1){
      int t = __shfl_up(v, ofs, 64);
      if (lane >= ofs) v += t;
    }
    if (lane == 63) wincl[wv] = v;
    __syncthreads();
    if (wv == 0 && lane < 16){
      int s = wincl[lane];
      #pragma unroll
      for (int ofs = 1; ofs < 16; ofs <<= 1){
        int t = __shfl_up(s, ofs, 64);
        if (lane >= ofs) s += t;
      }
      wincl[lane] = s;
    }
    __syncthreads();
    int woff = wv ? wincl[wv - 1] : 0;
    if (i < n) out[i] = carry + woff + v - x;   // exclusive
    carry += wincl[15];
    __syncthreads();
  }
  if (tid == 0) out[n] = carry;
  if (blockIdx.x == 1){
    for (int i = tid; i < n; i += 1024){
      int d = in1[i];
      dinv[i] = d > 0 ? 1.f / sqrtf((float)d) : 0.f;
    }
  }
}

// ---------------- fused CSR fill: both axes in one edge pass ----------------
__global__ void k_fill2(const int* __restrict__ row, const int* __restrict__ col,
                        const float* __restrict__ dist, const float* __restrict__ dinv,
                        const int* __restrict__ offs_r, int* __restrict__ cnt_r,
                        int* __restrict__ csr_col, float* __restrict__ csr_val,
                        const int* __restrict__ offs_c, int* __restrict__ cnt_c,
                        int* __restrict__ csr_row, int E){
  int e = blockIdx.x * blockDim.x + threadIdx.x;
  if (e < E){
    int r = row[e], c = col[e];
    int pr = offs_r[r] + atomicAdd(&cnt_r[r], 1);
    float d = dist[e];
    float t = expf(-d * d);
    float dw = expf(-t * t);            // exp(-exp(-d^2)^2), applied twice as in ref
    csr_col[pr] = c;
    csr_val[pr] = dw * dinv[r] * dinv[c];
    int pc = offs_c[c] + atomicAdd(&cnt_c[c], 1);
    csr_row[pc] = r;
  }
}

// ---------------- fused GCN layer: 16-wide ILP gather + GEMV + leaky + rownorm ----------------
__global__ __launch_bounds__(256) void k_gcn2(const int* __restrict__ offs, const int* __restrict__ csr_col,
                      const float* __restrict__ csr_val, const float* __restrict__ gfeat,
                      const float* __restrict__ W0, const float* __restrict__ W1,
                      float* __restrict__ out, int N){
  __shared__ float lw0[4096], lw1[4096];
  for (int i = threadIdx.x; i < 4096; i += 256){ lw0[i] = W0[i]; lw1[i] = W1[i]; }
  __syncthreads();
  int lane = threadIdx.x & 63, wave = threadIdx.x >> 6;
  int wgl = blockIdx.x * 4 + wave;
  int nw = gridDim.x * 4;
  for (int r = wgl; r < N; r += nw){
    int j0 = offs[r], j1 = offs[r + 1];
    float s = 0.f;
    for (int jb = j0; jb < j1; jb += 64){
      int rem = j1 - jb;
      int cnt = rem < 64 ? rem : 64;
      int jj = jb + lane;
      int   myc = (jj < j1) ? csr_col[jj] : 0;     // coalesced chunk load
      float myv = (jj < j1) ? csr_val[jj] : 0.f;
      int kk = 0;
      for (; kk + 16 <= cnt; kk += 16){
        int   c[16]; float v[16], f[16];
        #pragma unroll
        for (int u = 0; u < 16; u++){
          c[u] = __shfl(myc, kk + u, 64);
          v[u] = __shfl(myv, kk + u, 64);
        }
        #pragma unroll
        for (int u = 0; u < 16; u++) f[u] = gfeat[(long)c[u] * 64 + lane];
        #pragma unroll
        for (int u = 0; u < 16; u++) s += v[u] * f[u];
      }
      for (; kk + 8 <= cnt; kk += 8){
        int   c[8]; float v[8], f[8];
        #pragma unroll
        for (int u = 0; u < 8; u++){
          c[u] = __shfl(myc, kk + u, 64);
          v[u] = __shfl(myv, kk + u, 64);
        }
        #pragma unroll
        for (int u = 0; u < 8; u++) f[u] = gfeat[(long)c[u] * 64 + lane];
        #pragma unroll
        for (int u = 0; u < 8; u++) s += v[u] * f[u];
      }
      for (; kk < cnt; kk++){
        int cc = __shfl(myc, kk, 64);
        float vv = __shfl(myv, kk, 64);
        s += vv * gfeat[(long)cc * 64 + lane];
      }
    }
    float g = gfeat[(long)r * 64 + lane];
    float acc = 0.f;
    #pragma unroll
    for (int k = 0; k < 64; k++){
      float sk = __shfl(s, k, 64);
      float gk = __shfl(g, k, 64);
      acc += sk * lw0[k * 64 + lane] + gk * sk * lw1[k * 64 + lane];
    }
    float x = leakyf(acc);
    float nrm = sqrtf(wred(x * x));
    out[(long)r * 64 + lane] = x / fmaxf(nrm, 1e-12f);
  }
}

// ---------------- neighbor pooling: 16-wide ILP gather + mean ----------------
__global__ __launch_bounds__(256) void k_pool_gather(const int* __restrict__ offs,
                      const int* __restrict__ csr_row,
                      const float* __restrict__ poi, float* __restrict__ neigh, int N){
  int lane = threadIdx.x & 63, wave = threadIdx.x >> 6;
  int wgl = blockIdx.x * 4 + wave;
  int nw = gridDim.x * 4;
  for (int n = wgl; n < N; n += nw){
    int j0 = offs[n], j1 = offs[n + 1];
    float acc = 0.f;
    for (int jb = j0; jb < j1; jb += 64){
      int rem = j1 - jb;
      int cnt = rem < 64 ? rem : 64;
      int jj = jb + lane;
      int myc = (jj < j1) ? csr_row[jj] : 0;
      int kk = 0;
      for (; kk + 16 <= cnt; kk += 16){
        int c[16]; float f[16];
        #pragma unroll
        for (int u = 0; u < 16; u++) c[u] = __shfl(myc, kk + u, 64);
        #pragma unroll
        for (int u = 0; u < 16; u++) f[u] = poi[(long)c[u] * 64 + lane];
        #pragma unroll
        for (int u = 0; u < 16; u++) acc += f[u];
      }
      for (; kk + 8 <= cnt; kk += 8){
        int c[8]; float f[8];
        #pragma unroll
        for (int u = 0; u < 8; u++) c[u] = __shfl(myc, kk + u, 64);
        #pragma unroll
        for (int u = 0; u < 8; u++) f[u] = poi[(long)c[u] * 64 + lane];
        #pragma unroll
        for (int u = 0; u < 8; u++) acc += f[u];
      }
      for (; kk < cnt; kk++){
        int cc = __shfl(myc, kk, 64);
        acc += poi[(long)cc * 64 + lane];
      }
    }
    float inv = 1.f / fmaxf((float)(j1 - j0), 1.f);
    neigh[(long)n * 64 + lane] = acc * inv;
  }
}

// ---------------- generic [M,64]@[64,64] (+bias), optional row gather ----------------
template<bool GATHER>
__global__ __launch_bounds__(256) void k_gemm64(const float* __restrict__ X, const int* __restrict__ ridx,
                         const float* __restrict__ W, const float* __restrict__ bias,
                         float* __restrict__ Y, int M){
  __shared__ float lw[4096];
  for (int i = threadIdx.x; i < 4096; i += 256) lw[i] = W[i];
  __syncthreads();
  int lane = threadIdx.x & 63, wave = threadIdx.x >> 6;
  int wgl = blockIdx.x * 4 + wave;
  int nw = gridDim.x * 4;
  for (int r = wgl; r < M; r += nw){
    long src = GATHER ? (long)ridx[r] : (long)r;
    float x = X[src * 64 + lane];
    float acc = bias ? bias[lane] : 0.f;
    #pragma unroll
    for (int k = 0; k < 64; k++) acc += __shfl(x, k, 64) * lw[k * 64 + lane];
    Y[(long)r * 64 + lane] = acc;
  }
}

// ---------------- seq_query: per-batch attention + contiguous segment sum ----------------
// hq = q@W1 + b1 + b2 hoisted out of the per-position loop (q fixed per block).
template<bool GATHER_S>
__global__ __launch_bounds__(256) void k_seqq(const float* __restrict__ sbase, const int* __restrict__ sidx,
                       const float* __restrict__ qbase, const int* __restrict__ tar,
                       const float* __restrict__ W1, const float* __restrict__ b1,
                       const float* __restrict__ W2, const float* __restrict__ b2,
                       const float* __restrict__ a, const float* __restrict__ ab,
                       float* __restrict__ out, int L){
  __shared__ float lw1[4096], lw2[4096], la[64], lb[64];
  __shared__ float red[4][64];
  int tid = threadIdx.x;
  for (int i = tid; i < 4096; i += 256){ lw1[i] = W1[i]; lw2[i] = W2[i]; }
  if (tid < 64){ la[tid] = a[tid]; lb[tid] = b1[tid] + b2[tid]; }
  __syncthreads();
  int lane = tid & 63, wave = tid >> 6;
  int b = blockIdx.x;
  float q = qbase[(long)tar[b] * 64 + lane];
  float ab0 = ab[0];
  float hq = lb[lane];
  #pragma unroll
  for (int k = 0; k < 64; k++) hq += __shfl(q, k, 64) * lw1[k * 64 + lane];
  float acc = 0.f;
  for (int tl = wave; tl < L; tl += 4){
    int t = b * L + tl;
    long srow = GATHER_S ? (long)sidx[t] : (long)t;
    float s = sbase[srow * 64 + lane];
    float h = hq;
    #pragma unroll
    for (int k = 0; k < 64; k++) h += __shfl(s, k, 64) * lw2[k * 64 + lane];
    float sg = sigmf(h);
    float w = wred(sg * la[lane]) + ab0;
    acc += w * s;
  }
  red[wave][lane] = acc;
  __syncthreads();
  if (tid < 64)
    out[(long)b * 64 + tid] = red[0][tid] + red[1][tid] + red[2][tid] + red[3][tid];
}

// ---------------- per-batch mean pools (two sources, same indices) ----------------
__global__ __launch_bounds__(256) void k_pool(const float* __restrict__ neigh, const float* __restrict__ poi,
                       const int* __restrict__ sidx, float* __restrict__ p1,
                       float* __restrict__ p2, int L){
  __shared__ float r1[4][64], r2[4][64];
  int tid = threadIdx.x, lane = tid & 63, wave = tid >> 6, b = blockIdx.x;
  float a1 = 0.f, a2 = 0.f;
  for (int tl = wave; tl < L; tl += 4){
    long idx = sidx[b * L + tl];
    a1 += neigh[idx * 64 + lane];
    a2 += poi[idx * 64 + lane];
  }
  r1[wave][lane] = a1; r2[wave][lane] = a2;
  __syncthreads();
  float inv = 1.f / (float)L;
  if (tid < 64){
    p1[(long)b * 64 + tid] = (r1[0][tid] + r1[1][tid] + r1[2][tid] + r1[3][tid]) * inv;
    p2[(long)b * 64 + tid] = (r2[0][tid] + r2[1][tid] + r2[2][tid] + r2[3][tid]) * inv;
  }
}

// ---------------- GGC message scatter over T session edges ----------------
__global__ void k_edge_scatter(const int* __restrict__ e0, const int* __restrict__ e1,
                               const float* __restrict__ hw, float* __restrict__ m, int T){
  long gid = (long)blockIdx.x * blockDim.x + threadIdx.x;
  if (gid >= (long)T * 64) return;
  int e = (int)(gid >> 6), c = (int)(gid & 63);
  atomicAdd(&m[(long)e1[e] * 64 + c], hw[(long)e0[e] * 64 + c]);
}

// ---------------- GRU split, spill-free: gi = m @ wih^T + bih ----------------
__global__ __launch_bounds__(256) void k_gi(const float* __restrict__ m,
                     const float* __restrict__ wih, const float* __restrict__ bih,
                     float* __restrict__ gi, int T){
  __shared__ float lw[64 * 193];
  __shared__ float lb[192];
  int tid = threadIdx.x, lane = tid & 63, wave = tid >> 6;
  if (tid < 192) lb[tid] = bih[tid];
  for (int idx = tid; idx < 192 * 64; idx += 256){
    int j = idx >> 6, k = idx & 63;
    lw[k * 193 + j] = wih[idx];          // transposed + padded: conflict-free both ways
  }
  __syncthreads();
  int r0 = blockIdx.x * 4 + wave, nw = gridDim.x * 4;
  for (int t = r0; t < T; t += nw){
    float x = m[(long)t * 64 + lane];
    float a0 = lb[lane], a1 = lb[64 + lane], a2 = lb[128 + lane];
    #pragma unroll
    for (int k = 0; k < 64; k++){
      float xk = __shfl(x, k, 64);
      a0 += xk * lw[k * 193 + lane];
      a1 += xk * lw[k * 193 + 64 + lane];
      a2 += xk * lw[k * 193 + 128 + lane];
    }
    gi[(long)t * 192 + lane] = a0;
    gi[(long)t * 192 + 64 + lane] = a1;
    gi[(long)t * 192 + 128 + lane] = a2;
  }
}

// ---------------- GRU part 2: gh on the fly + fused gate math ----------------
__global__ __launch_bounds__(256) void k_gru2(const float* __restrict__ gi,
                       const float* __restrict__ poi, const int* __restrict__ sidx,
                       const float* __restrict__ whh, const float* __restrict__ bhh,
                       float* __restrict__ out, int T){
  __shared__ float lw[64 * 193];
  __shared__ float lb[192];
  int tid = threadIdx.x, lane = tid & 63, wave = tid >> 6;
  if (tid < 192) lb[tid] = bhh[tid];
  for (int idx = tid; idx < 192 * 64; idx += 256){
    int j = idx >> 6, k = idx & 63;
    lw[k * 193 + j] = whh[idx];
  }
  __syncthreads();
  int r0 = blockIdx.x * 4 + wave, nw = gridDim.x * 4;
  for (int t = r0; t < T; t += nw){
    float h = poi[(long)sidx[t] * 64 + lane];
    float b0 = lb[lane], b1 = lb[64 + lane], b2 = lb[128 + lane];
    #pragma unroll
    for (int k = 0; k < 64; k++){
      float hk = __shfl(h, k, 64);
      b0 += hk * lw[k * 193 + lane];
      b1 += hk * lw[k * 193 + 64 + lane];
      b2 += hk * lw[k * 193 + 128 + lane];
    }
    float r = sigmf(gi[(long)t * 192 + lane] + b0);
    float z = sigmf(gi[(long)t * 192 + 64 + lane] + b1);
    float n = tanhf(gi[(long)t * 192 + 128 + lane] + r * b2);   // n = tanh(i_n + r*h_n)
    float nh = (1.f - z) * n + z * h;
    out[(long)t * 64 + lane] = leakyf(nh);
  }
}

// ---------------- final head: con_loss, MLP logits, passthrough outputs ----------------
__global__ __launch_bounds__(64) void k_final(
    const float* __restrict__ poi, const float* __restrict__ gf,
    const int* __restrict__ tar,
    const float* __restrict__ geo_enc, const float* __restrict__ sess_enc,
    const float* __restrict__ gpool, const float* __restrict__ spool,
    const float* __restrict__ mW1, const float* __restrict__ mb1,
    const float* __restrict__ mW2, const float* __restrict__ mb2,
    const float* __restrict__ y, float* __restrict__ out, int B){
  int b = blockIdx.x, c = threadIdx.x;
  long tp = tar[b];
  long offT = 3L * B, offG = 3L * B + (long)B * 64;
  long offGP = 3L * B + 2L * B * 64, offSP = 3L * B + 3L * B * 64;
  float f0 = poi[tp * 64 + c];
  float f1 = gf[tp * 64 + c];
  float f2 = out[offSP + (long)b * 64 + c];   // sess_enc_p (already written)
  float f3 = out[offGP + (long)b * 64 + c];   // geo_enc_p
  float ge = geo_enc[(long)b * 64 + c], se = sess_enc[(long)b * 64 + c];
  float gp = gpool[(long)b * 64 + c], sp = spool[(long)b * 64 + c];
  float d1 = wred(ge * sp);
  float d2 = wred(ge * gp);
  float d3 = wred(se * gp);
  float d4 = wred(se * sp);
  float con = softplusf(d1 - d2) + softplusf(d3 - d4);
  float acc = mb1[c];
  #pragma unroll
  for (int k = 0; k < 64; k++){
    acc += __shfl(f0, k, 64) * mW1[k * 64 + c];
    acc += __shfl(f1, k, 64) * mW1[(64 + k) * 64 + c];
    acc += __shfl(f2, k, 64) * mW1[(128 + k) * 64 + c];
    acc += __shfl(f3, k, 64) * mW1[(192 + k) * 64 + c];
  }
  float hid = leakyf(acc);
  float lsum = wred(hid * mW2[c]);
  if (c == 0){
    out[b] = lsum + mb2[0];
    out[B + b] = con;
    out[2L * B + b] = y[b];
  }
  out[offT + (long)b * 64 + c] = f0;
  out[offG + (long)b * 64 + c] = f1;
}

extern "C" void kernel_launch(void* const* d_in, const int* in_sizes, int n_in,
                              void* d_out, int out_size, void* d_ws, size_t ws_size,
                              hipStream_t stream){
  const int*   sess_idx = (const int*)d_in[0];
  const int*   edges    = (const int*)d_in[1];
  const int*   tar_poi  = (const int*)d_in[3];
  const float* y        = (const float*)d_in[4];
  const int*   eidx     = (const int*)d_in[5];
  const float* dist     = (const float*)d_in[6];
  const float* poi      = (const float*)d_in[7];
  const float* geoW0    = (const float*)d_in[8];
  const float* geoW1    = (const float*)d_in[9];
  const float* ggcW     = (const float*)d_in[10];
  const float* wih      = (const float*)d_in[11];
  const float* whh      = (const float*)d_in[12];
  const float* bih      = (const float*)d_in[13];
  const float* bhh      = (const float*)d_in[14];
  const float* geoqW1   = (const float*)d_in[15];
  const float* geoqb1   = (const float*)d_in[16];
  const float* geoqW2   = (const float*)d_in[17];
  const float* geoqb2   = (const float*)d_in[18];
  const float* geoqa    = (const float*)d_in[19];
  const float* geoqab   = (const float*)d_in[20];
  const float* sessqW1  = (const float*)d_in[21];
  const float* sessqb1  = (const float*)d_in[22];
  const float* sessqW2  = (const float*)d_in[23];
  const float* sessqb2  = (const float*)d_in[24];
  const float* sessqa   = (const float*)d_in[25];
  const float* sessqab  = (const float*)d_in[26];
  const float* geo_proj = (const float*)d_in[27];
  const float* sess_proj= (const float*)d_in[28];
  const float* mW1      = (const float*)d_in[29];
  const float* mb1      = (const float*)d_in[30];
  const float* mW2      = (const float*)d_in[31];
  const float* mb2      = (const float*)d_in[32];

  const int T = in_sizes[0];
  const int B = in_sizes[3];
  const int E = in_sizes[5] / 2;
  const int N = in_sizes[7] / 64;
  const int G = in_sizes[8] / 4096;
  const int L = T / B;
  const int* erow = eidx;
  const int* ecol = eidx + E;
  const int* e0 = edges;
  const int* e1 = edges + T;

  // workspace carve-out (256B aligned).
  // gi (T*192 floats = 25.2MB) aliases gf0+csr_col+csr_val (26MB, dead post-GCN).
  // poolbuf serves as neigh (pooling) then mbuf (GGC); sessh aliases hw
  // (hw dead after k_edge_scatter, sessh written later by k_gru2).
  // Total ≈ 68 MB.
  char* w = (char*)d_ws;
  size_t off = 0;
  auto nxt = [&](size_t bytes)->void*{
    void* p = w + off; off = (off + bytes + 255) & ~(size_t)255; return p;
  };
  int*   deg_row = (int*)  nxt((size_t)N * 4);          // reused as cnt_row
  int*   deg_col = (int*)  nxt((size_t)N * 4);          // reused as cnt_col
  int*   offs_r  = (int*)  nxt((size_t)(N + 1) * 4);
  int*   offs_c  = (int*)  nxt((size_t)(N + 1) * 4);
  float* dinv    = (float*)nxt((size_t)N * 4);
  float* gf1     = (float*)nxt((size_t)N * 256);        // final geo_feat lands here
  float* geo_enc = (float*)nxt((size_t)B * 256);
  float* sess_enc= (float*)nxt((size_t)B * 256);
  float* p1      = (float*)nxt((size_t)B * 256);
  float* p2      = (float*)nxt((size_t)B * 256);
  float* gpool   = (float*)nxt((size_t)B * 256);
  float* spool   = (float*)nxt((size_t)B * 256);
  float* gf0     = (float*)nxt((size_t)N * 256);        // ┐
  int*   csr_col = (int*)  nxt((size_t)E * 4);          // ├ gi aliases this span
  float* csr_val = (float*)nxt((size_t)E * 4);          // ┘ (26.0MB >= 25.2MB)
  int*   csr_row = (int*)  nxt((size_t)E * 4);
  float* poolbuf = (float*)nxt((size_t)N * 256);        // neigh, then mbuf (T*256 <= N*256)
  float* hw      = (float*)nxt((size_t)T * 256);        // then sessh
  float* gi      = gf0;
  float* neigh   = poolbuf;
  float* mbuf    = poolbuf;
  float* sessh   = hw;
  float* outf    = (float*)d_out;

  const long offGP = 3L * B + 2L * B * 64;
  const long offSP = 3L * B + 3L * B * 64;

  // 1. degrees -> offsets (+dinv) -> fused CSR fill
  hipMemsetAsync(deg_row, 0, (size_t)N * 4, stream);
  hipMemsetAsync(deg_col, 0, (size_t)N * 4, stream);
  k_deg2<<<CDIV(E,256),256,0,stream>>>(erow, ecol, deg_row, deg_col, E);
  k_scan2<<<2,1024,0,stream>>>(deg_row, offs_r, deg_col, offs_c, dinv, N);
  hipMemsetAsync(deg_row, 0, (size_t)N * 4, stream);    // reuse as fill counters
  hipMemsetAsync(deg_col, 0, (size_t)N * 4, stream);
  k_fill2<<<CDIV(E,256),256,0,stream>>>(erow, ecol, dist, dinv,
                                        offs_r, deg_row, csr_col, csr_val,
                                        offs_c, deg_col, csr_row, E);

  // 2. Geo-GCN layers, gather form (ping-pong so final layer lands in gf1)
  const float* cur = poi;
  float* nextb = (G & 1) ? gf1 : gf0;
  for (int g = 0; g < G; g++){
    k_gcn2<<<2048,256,0,stream>>>(offs_r, csr_col, csr_val, cur,
                                  geoW0 + (size_t)g * 4096, geoW1 + (size_t)g * 4096,
                                  nextb, N);
    cur = nextb;
    nextb = (nextb == gf0) ? gf1 : gf0;
  }
  const float* gf = cur;   // == gf1

  // 3. seq_query (geo) -> geo_enc ; projection -> out geo_enc_p
  k_seqq<true><<<B,256,0,stream>>>(gf, sess_idx, gf, tar_poi,
                                   geoqW1, geoqb1, geoqW2, geoqb2, geoqa, geoqab,
                                   geo_enc, L);
  k_gemm64<false><<<CDIV(B,4),256,0,stream>>>(geo_enc, nullptr, geo_proj, nullptr,
                                              outf + offGP, B);

  // 4. neighbor pooling, gather form (mean fused via offsets)
  k_pool_gather<<<2048,256,0,stream>>>(offs_c, csr_row, poi, neigh, N);
  k_pool<<<B,256,0,stream>>>(neigh, poi, sess_idx, p1, p2, L);
  k_gemm64<false><<<CDIV(B,4),256,0,stream>>>(p1, nullptr, geo_proj, nullptr, gpool, B);
  k_gemm64<false><<<CDIV(B,4),256,0,stream>>>(p2, nullptr, sess_proj, nullptr, spool, B);

  // 5. GatedGraphConv + GRU (poolbuf becomes mbuf; gi aliases gf0+csr_col+csr_val)
  k_gemm64<true><<<2048,256,0,stream>>>(poi, sess_idx, ggcW, nullptr, hw, T);
  hipMemsetAsync(mbuf, 0, (size_t)T * 256, stream);
  k_edge_scatter<<<(int)CDIV((long)T*64,256),256,0,stream>>>(e0, e1, hw, mbuf, T);
  k_gi<<<1024,256,0,stream>>>(mbuf, wih, bih, gi, T);
  k_gru2<<<1024,256,0,stream>>>(gi, poi, sess_idx, whh, bhh, sessh, T);

  // 6. seq_query (sess) -> sess_enc ; projection -> out sess_enc_p
  k_seqq<false><<<B,256,0,stream>>>(sessh, nullptr, poi, tar_poi,
                                    sessqW1, sessqb1, sessqW2, sessqb2, sessqa, sessqab,
                                    sess_enc, L);
  k_gemm64<false><<<CDIV(B,4),256,0,stream>>>(sess_enc, nullptr, sess_proj, nullptr,
                                              outf + offSP, B);

  // 7. final head
  k_final<<<B,64,0,stream>>>(poi, gf, tar_poi, geo_enc, sess_enc, gpool, spool,
                             mW1, mb1, mW2, mb2, y, outf, B);
}

// Round 8
// 1068.491 us; speedup vs baseline: 1.2027x; 1.2027x over previous
//
#include <hip/hip_runtime.h>
#include <math.h>

#define CDIV(a,b) (((a)+(b)-1)/(b))

__device__ __forceinline__ float wred(float v){
  #pragma unroll
  for (int o = 32; o; o >>= 1) v += __shfl_xor(v, o, 64);
  return v;
}
__device__ __forceinline__ float leakyf(float x){ return x > 0.f ? x : 0.01f * x; }
__device__ __forceinline__ float sigmf(float x){ return 1.f / (1.f + expf(-x)); }
__device__ __forceinline__ float softplusf(float x){
  return fmaxf(x, 0.f) + log1pf(expf(-fabsf(x)));
}

// ---------------- degrees (both axes in one pass) ----------------
__global__ void k_deg2(const int* __restrict__ row, const int* __restrict__ col,
                       int* __restrict__ deg_row, int* __restrict__ deg_col, int E){
  int e = blockIdx.x * blockDim.x + threadIdx.x;
  if (e < E){
    atomicAdd(&deg_row[row[e]], 1);
    atomicAdd(&deg_col[col[e]], 1);
  }
}

// ---------------- exclusive scan of two N-arrays; block 1 also emits dinv ----------------
__global__ __launch_bounds__(1024) void k_scan2(const int* __restrict__ in0, int* __restrict__ out0,
                        const int* __restrict__ in1, int* __restrict__ out1,
                        float* __restrict__ dinv, int n){
  __shared__ int wincl[16];
  const int* in  = blockIdx.x ? in1 : in0;
  int* out       = blockIdx.x ? out1 : out0;
  int tid = threadIdx.x, lane = tid & 63, wv = tid >> 6;
  int carry = 0;
  for (int base = 0; base < n; base += 1024){
    int i = base + tid;
    int x = (i < n) ? in[i] : 0;
    int v = x;
    #pragma unroll
    for (int ofs = 1; ofs < 64; ofs <<= 1){
      int t = __shfl_up(v, ofs, 64);
      if (lane >= ofs) v += t;
    }
    if (lane == 63) wincl[wv] = v;
    __syncthreads();
    if (wv == 0 && lane < 16){
      int s = wincl[lane];
      #pragma unroll
      for (int ofs = 1; ofs < 16; ofs <<= 1){
        int t = __shfl_up(s, ofs, 64);
        if (lane >= ofs) s += t;
      }
      wincl[lane] = s;
    }
    __syncthreads();
    int woff = wv ? wincl[wv - 1] : 0;
    if (i < n) out[i] = carry + woff + v - x;   // exclusive
    carry += wincl[15];
    __syncthreads();
  }
  if (tid == 0) out[n] = carry;
  if (blockIdx.x == 1){
    for (int i = tid; i < n; i += 1024){
      int d = in1[i];
      dinv[i] = d > 0 ? 1.f / sqrtf((float)d) : 0.f;
    }
  }
}

// ---------------- fused CSR fill: both axes in one edge pass ----------------
__global__ void k_fill2(const int* __restrict__ row, const int* __restrict__ col,
                        const float* __restrict__ dist, const float* __restrict__ dinv,
                        const int* __restrict__ offs_r, int* __restrict__ cnt_r,
                        int* __restrict__ csr_col, float* __restrict__ csr_val,
                        const int* __restrict__ offs_c, int* __restrict__ cnt_c,
                        int* __restrict__ csr_row, int E){
  int e = blockIdx.x * blockDim.x + threadIdx.x;
  if (e < E){
    int r = row[e], c = col[e];
    int pr = offs_r[r] + atomicAdd(&cnt_r[r], 1);
    float d = dist[e];
    float t = expf(-d * d);
    float dw = expf(-t * t);            // exp(-exp(-d^2)^2), applied twice as in ref
    csr_col[pr] = c;
    csr_val[pr] = dw * dinv[r] * dinv[c];
    int pc = offs_c[c] + atomicAdd(&cnt_c[c], 1);
    csr_row[pc] = r;
  }
}

// ---------------- fused GCN layer: 8-wide ILP gather + GEMV + leaky + rownorm ----------------
// 512-thread blocks: 8 waves share one 32KB weight-LDS copy -> 4 blocks/CU = 32 waves
// (vs 256-thread blocks where LDS capped residency at 20 waves/CU).
__global__ __launch_bounds__(512) void k_gcn2(const int* __restrict__ offs, const int* __restrict__ csr_col,
                      const float* __restrict__ csr_val, const float* __restrict__ gfeat,
                      const float* __restrict__ W0, const float* __restrict__ W1,
                      float* __restrict__ out, int N){
  __shared__ float lw0[4096], lw1[4096];
  for (int i = threadIdx.x; i < 4096; i += 512){ lw0[i] = W0[i]; lw1[i] = W1[i]; }
  __syncthreads();
  int lane = threadIdx.x & 63, wave = threadIdx.x >> 6;
  int wgl = blockIdx.x * 8 + wave;
  int nw = gridDim.x * 8;
  for (int r = wgl; r < N; r += nw){
    int j0 = offs[r], j1 = offs[r + 1];
    float s = 0.f;
    for (int jb = j0; jb < j1; jb += 64){
      int rem = j1 - jb;
      int cnt = rem < 64 ? rem : 64;
      int jj = jb + lane;
      int   myc = (jj < j1) ? csr_col[jj] : 0;     // coalesced chunk load
      float myv = (jj < j1) ? csr_val[jj] : 0.f;
      int kk = 0;
      for (; kk + 8 <= cnt; kk += 8){
        int c0 = __shfl(myc, kk+0, 64), c1 = __shfl(myc, kk+1, 64),
            c2 = __shfl(myc, kk+2, 64), c3 = __shfl(myc, kk+3, 64),
            c4 = __shfl(myc, kk+4, 64), c5 = __shfl(myc, kk+5, 64),
            c6 = __shfl(myc, kk+6, 64), c7 = __shfl(myc, kk+7, 64);
        float v0 = __shfl(myv, kk+0, 64), v1 = __shfl(myv, kk+1, 64),
              v2 = __shfl(myv, kk+2, 64), v3 = __shfl(myv, kk+3, 64),
              v4 = __shfl(myv, kk+4, 64), v5 = __shfl(myv, kk+5, 64),
              v6 = __shfl(myv, kk+6, 64), v7 = __shfl(myv, kk+7, 64);
        float f0 = gfeat[(long)c0 * 64 + lane];
        float f1 = gfeat[(long)c1 * 64 + lane];
        float f2 = gfeat[(long)c2 * 64 + lane];
        float f3 = gfeat[(long)c3 * 64 + lane];
        float f4 = gfeat[(long)c4 * 64 + lane];
        float f5 = gfeat[(long)c5 * 64 + lane];
        float f6 = gfeat[(long)c6 * 64 + lane];
        float f7 = gfeat[(long)c7 * 64 + lane];
        s += v0 * f0; s += v1 * f1; s += v2 * f2; s += v3 * f3;
        s += v4 * f4; s += v5 * f5; s += v6 * f6; s += v7 * f7;
      }
      for (; kk < cnt; kk++){
        int c = __shfl(myc, kk, 64);
        float v = __shfl(myv, kk, 64);
        s += v * gfeat[(long)c * 64 + lane];
      }
    }
    float g = gfeat[(long)r * 64 + lane];
    float acc = 0.f;
    #pragma unroll
    for (int k = 0; k < 64; k++){
      float sk = __shfl(s, k, 64);
      float gk = __shfl(g, k, 64);
      acc += sk * lw0[k * 64 + lane] + gk * sk * lw1[k * 64 + lane];
    }
    float x = leakyf(acc);
    float nrm = sqrtf(wred(x * x));
    out[(long)r * 64 + lane] = x / fmaxf(nrm, 1e-12f);
  }
}

// ---------------- neighbor pooling: 8-wide ILP gather + mean ----------------
__global__ __launch_bounds__(256) void k_pool_gather(const int* __restrict__ offs,
                      const int* __restrict__ csr_row,
                      const float* __restrict__ poi, float* __restrict__ neigh, int N){
  int lane = threadIdx.x & 63, wave = threadIdx.x >> 6;
  int wgl = blockIdx.x * 4 + wave;
  int nw = gridDim.x * 4;
  for (int n = wgl; n < N; n += nw){
    int j0 = offs[n], j1 = offs[n + 1];
    float acc = 0.f;
    for (int jb = j0; jb < j1; jb += 64){
      int rem = j1 - jb;
      int cnt = rem < 64 ? rem : 64;
      int jj = jb + lane;
      int myc = (jj < j1) ? csr_row[jj] : 0;
      int kk = 0;
      for (; kk + 8 <= cnt; kk += 8){
        int c0 = __shfl(myc, kk+0, 64), c1 = __shfl(myc, kk+1, 64),
            c2 = __shfl(myc, kk+2, 64), c3 = __shfl(myc, kk+3, 64),
            c4 = __shfl(myc, kk+4, 64), c5 = __shfl(myc, kk+5, 64),
            c6 = __shfl(myc, kk+6, 64), c7 = __shfl(myc, kk+7, 64);
        float f0 = poi[(long)c0 * 64 + lane];
        float f1 = poi[(long)c1 * 64 + lane];
        float f2 = poi[(long)c2 * 64 + lane];
        float f3 = poi[(long)c3 * 64 + lane];
        float f4 = poi[(long)c4 * 64 + lane];
        float f5 = poi[(long)c5 * 64 + lane];
        float f6 = poi[(long)c6 * 64 + lane];
        float f7 = poi[(long)c7 * 64 + lane];
        acc += f0 + f1 + f2 + f3 + f4 + f5 + f6 + f7;
      }
      for (; kk < cnt; kk++){
        int c = __shfl(myc, kk, 64);
        acc += poi[(long)c * 64 + lane];
      }
    }
    float inv = 1.f / fmaxf((float)(j1 - j0), 1.f);
    neigh[(long)n * 64 + lane] = acc * inv;
  }
}

// ---------------- generic [M,64]@[64,64] (+bias), optional row gather ----------------
template<bool GATHER>
__global__ __launch_bounds__(256) void k_gemm64(const float* __restrict__ X, const int* __restrict__ ridx,
                         const float* __restrict__ W, const float* __restrict__ bias,
                         float* __restrict__ Y, int M){
  __shared__ float lw[4096];
  for (int i = threadIdx.x; i < 4096; i += 256) lw[i] = W[i];
  __syncthreads();
  int lane = threadIdx.x & 63, wave = threadIdx.x >> 6;
  int wgl = blockIdx.x * 4 + wave;
  int nw = gridDim.x * 4;
  for (int r = wgl; r < M; r += nw){
    long src = GATHER ? (long)ridx[r] : (long)r;
    float x = X[src * 64 + lane];
    float acc = bias ? bias[lane] : 0.f;
    #pragma unroll
    for (int k = 0; k < 64; k++) acc += __shfl(x, k, 64) * lw[k * 64 + lane];
    Y[(long)r * 64 + lane] = acc;
  }
}

// ---------------- seq_query: per-batch attention + contiguous segment sum ----------------
// hq = q@W1 + b1 + b2 hoisted out of the per-position loop (q fixed per block).
template<bool GATHER_S>
__global__ __launch_bounds__(256) void k_seqq(const float* __restrict__ sbase, const int* __restrict__ sidx,
                       const float* __restrict__ qbase, const int* __restrict__ tar,
                       const float* __restrict__ W1, const float* __restrict__ b1,
                       const float* __restrict__ W2, const float* __restrict__ b2,
                       const float* __restrict__ a, const float* __restrict__ ab,
                       float* __restrict__ out, int L){
  __shared__ float lw1[4096], lw2[4096], la[64], lb[64];
  __shared__ float red[4][64];
  int tid = threadIdx.x;
  for (int i = tid; i < 4096; i += 256){ lw1[i] = W1[i]; lw2[i] = W2[i]; }
  if (tid < 64){ la[tid] = a[tid]; lb[tid] = b1[tid] + b2[tid]; }
  __syncthreads();
  int lane = tid & 63, wave = tid >> 6;
  int b = blockIdx.x;
  float q = qbase[(long)tar[b] * 64 + lane];
  float ab0 = ab[0];
  float hq = lb[lane];
  #pragma unroll
  for (int k = 0; k < 64; k++) hq += __shfl(q, k, 64) * lw1[k * 64 + lane];
  float acc = 0.f;
  for (int tl = wave; tl < L; tl += 4){
    int t = b * L + tl;
    long srow = GATHER_S ? (long)sidx[t] : (long)t;
    float s = sbase[srow * 64 + lane];
    float h = hq;
    #pragma unroll
    for (int k = 0; k < 64; k++) h += __shfl(s, k, 64) * lw2[k * 64 + lane];
    float sg = sigmf(h);
    float w = wred(sg * la[lane]) + ab0;
    acc += w * s;
  }
  red[wave][lane] = acc;
  __syncthreads();
  if (tid < 64)
    out[(long)b * 64 + tid] = red[0][tid] + red[1][tid] + red[2][tid] + red[3][tid];
}

// ---------------- per-batch mean pools (two sources, same indices) ----------------
__global__ __launch_bounds__(256) void k_pool(const float* __restrict__ neigh, const float* __restrict__ poi,
                       const int* __restrict__ sidx, float* __restrict__ p1,
                       float* __restrict__ p2, int L){
  __shared__ float r1[4][64], r2[4][64];
  int tid = threadIdx.x, lane = tid & 63, wave = tid >> 6, b = blockIdx.x;
  float a1 = 0.f, a2 = 0.f;
  for (int tl = wave; tl < L; tl += 4){
    long idx = sidx[b * L + tl];
    a1 += neigh[idx * 64 + lane];
    a2 += poi[idx * 64 + lane];
  }
  r1[wave][lane] = a1; r2[wave][lane] = a2;
  __syncthreads();
  float inv = 1.f / (float)L;
  if (tid < 64){
    p1[(long)b * 64 + tid] = (r1[0][tid] + r1[1][tid] + r1[2][tid] + r1[3][tid]) * inv;
    p2[(long)b * 64 + tid] = (r2[0][tid] + r2[1][tid] + r2[2][tid] + r2[3][tid]) * inv;
  }
}

// ---------------- GGC message scatter over T session edges ----------------
__global__ void k_edge_scatter(const int* __restrict__ e0, const int* __restrict__ e1,
                               const float* __restrict__ hw, float* __restrict__ m, int T){
  long gid = (long)blockIdx.x * blockDim.x + threadIdx.x;
  if (gid >= (long)T * 64) return;
  int e = (int)(gid >> 6), c = (int)(gid & 63);
  atomicAdd(&m[(long)e1[e] * 64 + c], hw[(long)e0[e] * 64 + c]);
}

// ---------------- GRU split, spill-free: gi = m @ wih^T + bih ----------------
__global__ __launch_bounds__(256) void k_gi(const float* __restrict__ m,
                     const float* __restrict__ wih, const float* __restrict__ bih,
                     float* __restrict__ gi, int T){
  __shared__ float lw[64 * 193];
  __shared__ float lb[192];
  int tid = threadIdx.x, lane = tid & 63, wave = tid >> 6;
  if (tid < 192) lb[tid] = bih[tid];
  for (int idx = tid; idx < 192 * 64; idx += 256){
    int j = idx >> 6, k = idx & 63;
    lw[k * 193 + j] = wih[idx];          // transposed + padded: conflict-free both ways
  }
  __syncthreads();
  int r0 = blockIdx.x * 4 + wave, nw = gridDim.x * 4;
  for (int t = r0; t < T; t += nw){
    float x = m[(long)t * 64 + lane];
    float a0 = lb[lane], a1 = lb[64 + lane], a2 = lb[128 + lane];
    #pragma unroll
    for (int k = 0; k < 64; k++){
      float xk = __shfl(x, k, 64);
      a0 += xk * lw[k * 193 + lane];
      a1 += xk * lw[k * 193 + 64 + lane];
      a2 += xk * lw[k * 193 + 128 + lane];
    }
    gi[(long)t * 192 + lane] = a0;
    gi[(long)t * 192 + 64 + lane] = a1;
    gi[(long)t * 192 + 128 + lane] = a2;
  }
}

// ---------------- GRU part 2: gh on the fly + fused gate math ----------------
__global__ __launch_bounds__(256) void k_gru2(const float* __restrict__ gi,
                       const float* __restrict__ poi, const int* __restrict__ sidx,
                       const float* __restrict__ whh, const float* __restrict__ bhh,
                       float* __restrict__ out, int T){
  __shared__ float lw[64 * 193];
  __shared__ float lb[192];
  int tid = threadIdx.x, lane = tid & 63, wave = tid >> 6;
  if (tid < 192) lb[tid] = bhh[tid];
  for (int idx = tid; idx < 192 * 64; idx += 256){
    int j = idx >> 6, k = idx & 63;
    lw[k * 193 + j] = whh[idx];
  }
  __syncthreads();
  int r0 = blockIdx.x * 4 + wave, nw = gridDim.x * 4;
  for (int t = r0; t < T; t += nw){
    float h = poi[(long)sidx[t] * 64 + lane];
    float b0 = lb[lane], b1 = lb[64 + lane], b2 = lb[128 + lane];
    #pragma unroll
    for (int k = 0; k < 64; k++){
      float hk = __shfl(h, k, 64);
      b0 += hk * lw[k * 193 + lane];
      b1 += hk * lw[k * 193 + 64 + lane];
      b2 += hk * lw[k * 193 + 128 + lane];
    }
    float r = sigmf(gi[(long)t * 192 + lane] + b0);
    float z = sigmf(gi[(long)t * 192 + 64 + lane] + b1);
    float n = tanhf(gi[(long)t * 192 + 128 + lane] + r * b2);   // n = tanh(i_n + r*h_n)
    float nh = (1.f - z) * n + z * h;
    out[(long)t * 64 + lane] = leakyf(nh);
  }
}

// ---------------- final head: con_loss, MLP logits, passthrough outputs ----------------
__global__ __launch_bounds__(64) void k_final(
    const float* __restrict__ poi, const float* __restrict__ gf,
    const int* __restrict__ tar,
    const float* __restrict__ geo_enc, const float* __restrict__ sess_enc,
    const float* __restrict__ gpool, const float* __restrict__ spool,
    const float* __restrict__ mW1, const float* __restrict__ mb1,
    const float* __restrict__ mW2, const float* __restrict__ mb2,
    const float* __restrict__ y, float* __restrict__ out, int B){
  int b = blockIdx.x, c = threadIdx.x;
  long tp = tar[b];
  long offT = 3L * B, offG = 3L * B + (long)B * 64;
  long offGP = 3L * B + 2L * B * 64, offSP = 3L * B + 3L * B * 64;
  float f0 = poi[tp * 64 + c];
  float f1 = gf[tp * 64 + c];
  float f2 = out[offSP + (long)b * 64 + c];   // sess_enc_p (already written)
  float f3 = out[offGP + (long)b * 64 + c];   // geo_enc_p
  float ge = geo_enc[(long)b * 64 + c], se = sess_enc[(long)b * 64 + c];
  float gp = gpool[(long)b * 64 + c], sp = spool[(long)b * 64 + c];
  float d1 = wred(ge * sp);
  float d2 = wred(ge * gp);
  float d3 = wred(se * gp);
  float d4 = wred(se * sp);
  float con = softplusf(d1 - d2) + softplusf(d3 - d4);
  float acc = mb1[c];
  #pragma unroll
  for (int k = 0; k < 64; k++){
    acc += __shfl(f0, k, 64) * mW1[k * 64 + c];
    acc += __shfl(f1, k, 64) * mW1[(64 + k) * 64 + c];
    acc += __shfl(f2, k, 64) * mW1[(128 + k) * 64 + c];
    acc += __shfl(f3, k, 64) * mW1[(192 + k) * 64 + c];
  }
  float hid = leakyf(acc);
  float lsum = wred(hid * mW2[c]);
  if (c == 0){
    out[b] = lsum + mb2[0];
    out[B + b] = con;
    out[2L * B + b] = y[b];
  }
  out[offT + (long)b * 64 + c] = f0;
  out[offG + (long)b * 64 + c] = f1;
}

extern "C" void kernel_launch(void* const* d_in, const int* in_sizes, int n_in,
                              void* d_out, int out_size, void* d_ws, size_t ws_size,
                              hipStream_t stream){
  const int*   sess_idx = (const int*)d_in[0];
  const int*   edges    = (const int*)d_in[1];
  const int*   tar_poi  = (const int*)d_in[3];
  const float* y        = (const float*)d_in[4];
  const int*   eidx     = (const int*)d_in[5];
  const float* dist     = (const float*)d_in[6];
  const float* poi      = (const float*)d_in[7];
  const float* geoW0    = (const float*)d_in[8];
  const float* geoW1    = (const float*)d_in[9];
  const float* ggcW     = (const float*)d_in[10];
  const float* wih      = (const float*)d_in[11];
  const float* whh      = (const float*)d_in[12];
  const float* bih      = (const float*)d_in[13];
  const float* bhh      = (const float*)d_in[14];
  const float* geoqW1   = (const float*)d_in[15];
  const float* geoqb1   = (const float*)d_in[16];
  const float* geoqW2   = (const float*)d_in[17];
  const float* geoqb2   = (const float*)d_in[18];
  const float* geoqa    = (const float*)d_in[19];
  const float* geoqab   = (const float*)d_in[20];
  const float* sessqW1  = (const float*)d_in[21];
  const float* sessqb1  = (const float*)d_in[22];
  const float* sessqW2  = (const float*)d_in[23];
  const float* sessqb2  = (const float*)d_in[24];
  const float* sessqa   = (const float*)d_in[25];
  const float* sessqab  = (const float*)d_in[26];
  const float* geo_proj = (const float*)d_in[27];
  const float* sess_proj= (const float*)d_in[28];
  const float* mW1      = (const float*)d_in[29];
  const float* mb1      = (const float*)d_in[30];
  const float* mW2      = (const float*)d_in[31];
  const float* mb2      = (const float*)d_in[32];

  const int T = in_sizes[0];
  const int B = in_sizes[3];
  const int E = in_sizes[5] / 2;
  const int N = in_sizes[7] / 64;
  const int G = in_sizes[8] / 4096;
  const int L = T / B;
  const int* erow = eidx;
  const int* ecol = eidx + E;
  const int* e0 = edges;
  const int* e1 = edges + T;

  // workspace carve-out (256B aligned).
  // gi (T*192 floats = 25.2MB) aliases gf0+csr_col+csr_val (26MB, dead post-GCN).
  // poolbuf serves as neigh (pooling) then mbuf (GGC); sessh aliases hw
  // (hw dead after k_edge_scatter, sessh written later by k_gru2).
  // Total ≈ 68 MB.
  char* w = (char*)d_ws;
  size_t off = 0;
  auto nxt = [&](size_t bytes)->void*{
    void* p = w + off; off = (off + bytes + 255) & ~(size_t)255; return p;
  };
  int*   deg_row = (int*)  nxt((size_t)N * 4);          // reused as cnt_row
  int*   deg_col = (int*)  nxt((size_t)N * 4);          // reused as cnt_col
  int*   offs_r  = (int*)  nxt((size_t)(N + 1) * 4);
  int*   offs_c  = (int*)  nxt((size_t)(N + 1) * 4);
  float* dinv    = (float*)nxt((size_t)N * 4);
  float* gf1     = (float*)nxt((size_t)N * 256);        // final geo_feat lands here
  float* geo_enc = (float*)nxt((size_t)B * 256);
  float* sess_enc= (float*)nxt((size_t)B * 256);
  float* p1      = (float*)nxt((size_t)B * 256);
  float* p2      = (float*)nxt((size_t)B * 256);
  float* gpool   = (float*)nxt((size_t)B * 256);
  float* spool   = (float*)nxt((size_t)B * 256);
  float* gf0     = (float*)nxt((size_t)N * 256);        // ┐
  int*   csr_col = (int*)  nxt((size_t)E * 4);          // ├ gi aliases this span
  float* csr_val = (float*)nxt((size_t)E * 4);          // ┘ (26.0MB >= 25.2MB)
  int*   csr_row = (int*)  nxt((size_t)E * 4);
  float* poolbuf = (float*)nxt((size_t)N * 256);        // neigh, then mbuf (T*256 <= N*256)
  float* hw      = (float*)nxt((size_t)T * 256);        // then sessh
  float* gi      = gf0;
  float* neigh   = poolbuf;
  float* mbuf    = poolbuf;
  float* sessh   = hw;
  float* outf    = (float*)d_out;

  const long offGP = 3L * B + 2L * B * 64;
  const long offSP = 3L * B + 3L * B * 64;

  // 1. degrees -> offsets (+dinv) -> fused CSR fill
  hipMemsetAsync(deg_row, 0, (size_t)N * 4, stream);
  hipMemsetAsync(deg_col, 0, (size_t)N * 4, stream);
  k_deg2<<<CDIV(E,256),256,0,stream>>>(erow, ecol, deg_row, deg_col, E);
  k_scan2<<<2,1024,0,stream>>>(deg_row, offs_r, deg_col, offs_c, dinv, N);
  hipMemsetAsync(deg_row, 0, (size_t)N * 4, stream);    // reuse as fill counters
  hipMemsetAsync(deg_col, 0, (size_t)N * 4, stream);
  k_fill2<<<CDIV(E,256),256,0,stream>>>(erow, ecol, dist, dinv,
                                        offs_r, deg_row, csr_col, csr_val,
                                        offs_c, deg_col, csr_row, E);

  // 2. Geo-GCN layers, gather form (ping-pong so final layer lands in gf1)
  const float* cur = poi;
  float* nextb = (G & 1) ? gf1 : gf0;
  for (int g = 0; g < G; g++){
    k_gcn2<<<1024,512,0,stream>>>(offs_r, csr_col, csr_val, cur,
                                  geoW0 + (size_t)g * 4096, geoW1 + (size_t)g * 4096,
                                  nextb, N);
    cur = nextb;
    nextb = (nextb == gf0) ? gf1 : gf0;
  }
  const float* gf = cur;   // == gf1

  // 3. seq_query (geo) -> geo_enc ; projection -> out geo_enc_p
  k_seqq<true><<<B,256,0,stream>>>(gf, sess_idx, gf, tar_poi,
                                   geoqW1, geoqb1, geoqW2, geoqb2, geoqa, geoqab,
                                   geo_enc, L);
  k_gemm64<false><<<CDIV(B,4),256,0,stream>>>(geo_enc, nullptr, geo_proj, nullptr,
                                              outf + offGP, B);

  // 4. neighbor pooling, gather form (mean fused via offsets)
  k_pool_gather<<<2048,256,0,stream>>>(offs_c, csr_row, poi, neigh, N);
  k_pool<<<B,256,0,stream>>>(neigh, poi, sess_idx, p1, p2, L);
  k_gemm64<false><<<CDIV(B,4),256,0,stream>>>(p1, nullptr, geo_proj, nullptr, gpool, B);
  k_gemm64<false><<<CDIV(B,4),256,0,stream>>>(p2, nullptr, sess_proj, nullptr, spool, B);

  // 5. GatedGraphConv + GRU (poolbuf becomes mbuf; gi aliases gf0+csr_col+csr_val)
  k_gemm64<true><<<2048,256,0,stream>>>(poi, sess_idx, ggcW, nullptr, hw, T);
  hipMemsetAsync(mbuf, 0, (size_t)T * 256, stream);
  k_edge_scatter<<<(int)CDIV((long)T*64,256),256,0,stream>>>(e0, e1, hw, mbuf, T);
  k_gi<<<1024,256,0,stream>>>(mbuf, wih, bih, gi, T);
  k_gru2<<<1024,256,0,stream>>>(gi, poi, sess_idx, whh, bhh, sessh, T);

  // 6. seq_query (sess) -> sess_enc ; projection -> out sess_enc_p
  k_seqq<false><<<B,256,0,stream>>>(sessh, nullptr, poi, tar_poi,
                                    sessqW1, sessqb1, sessqW2, sessqb2, sessqa, sessqab,
                                    sess_enc, L);
  k_gemm64<false><<<CDIV(B,4),256,0,stream>>>(sess_enc, nullptr, sess_proj, nullptr,
                                              outf + offSP, B);

  // 7. final head
  k_final<<<B,64,0,stream>>>(poi, gf, tar_poi, geo_enc, sess_enc, gpool, spool,
                             mW1, mb1, mW2, mb2, y, outf, B);
}

// Round 9
// 945.243 us; speedup vs baseline: 1.3595x; 1.1304x over previous
//
#include <hip/hip_runtime.h>
#include <math.h>

#define CDIV(a,b) (((a)+(b)-1)/(b))

__device__ __forceinline__ float wred(float v){
  #pragma unroll
  for (int o = 32; o; o >>= 1) v += __shfl_xor(v, o, 64);
  return v;
}
__device__ __forceinline__ float leakyf(float x){ return x > 0.f ? x : 0.01f * x; }
__device__ __forceinline__ float sigmf(float x){ return 1.f / (1.f + expf(-x)); }
__device__ __forceinline__ float softplusf(float x){
  return fmaxf(x, 0.f) + log1pf(expf(-fabsf(x)));
}

// ---------------- degrees (both axes in one pass) ----------------
__global__ void k_deg2(const int* __restrict__ row, const int* __restrict__ col,
                       int* __restrict__ deg_row, int* __restrict__ deg_col, int E){
  int e = blockIdx.x * blockDim.x + threadIdx.x;
  if (e < E){
    atomicAdd(&deg_row[row[e]], 1);
    atomicAdd(&deg_col[col[e]], 1);
  }
}

// ---------------- exclusive scan of two N-arrays; block 1 also emits dinv ----------------
__global__ __launch_bounds__(1024) void k_scan2(const int* __restrict__ in0, int* __restrict__ out0,
                        const int* __restrict__ in1, int* __restrict__ out1,
                        float* __restrict__ dinv, int n){
  __shared__ int wincl[16];
  const int* in  = blockIdx.x ? in1 : in0;
  int* out       = blockIdx.x ? out1 : out0;
  int tid = threadIdx.x, lane = tid & 63, wv = tid >> 6;
  int carry = 0;
  for (int base = 0; base < n; base += 1024){
    int i = base + tid;
    int x = (i < n) ? in[i] : 0;
    int v = x;
    #pragma unroll
    for (int ofs = 1; ofs < 64; ofs <<= 1){
      int t = __shfl_up(v, ofs, 64);
      if (lane >= ofs) v += t;
    }
    if (lane == 63) wincl[wv] = v;
    __syncthreads();
    if (wv == 0 && lane < 16){
      int s = wincl[lane];
      #pragma unroll
      for (int ofs = 1; ofs < 16; ofs <<= 1){
        int t = __shfl_up(s, ofs, 64);
        if (lane >= ofs) s += t;
      }
      wincl[lane] = s;
    }
    __syncthreads();
    int woff = wv ? wincl[wv - 1] : 0;
    if (i < n) out[i] = carry + woff + v - x;   // exclusive
    carry += wincl[15];
    __syncthreads();
  }
  if (tid == 0) out[n] = carry;
  if (blockIdx.x == 1){
    for (int i = tid; i < n; i += 1024){
      int d = in1[i];
      dinv[i] = d > 0 ? 1.f / sqrtf((float)d) : 0.f;
    }
  }
}

// ---------------- fused CSR fill: both axes; (col,val) packed as one int2 write ----------------
__global__ void k_fill2(const int* __restrict__ row, const int* __restrict__ col,
                        const float* __restrict__ dist, const float* __restrict__ dinv,
                        const int* __restrict__ offs_r, int* __restrict__ cnt_r,
                        int2* __restrict__ csr_cv,
                        const int* __restrict__ offs_c, int* __restrict__ cnt_c,
                        int* __restrict__ csr_row, int E){
  int e = blockIdx.x * blockDim.x + threadIdx.x;
  if (e < E){
    int r = row[e], c = col[e];
    int pr = offs_r[r] + atomicAdd(&cnt_r[r], 1);
    float d = dist[e];
    float t = expf(-d * d);
    float dw = expf(-t * t);            // exp(-exp(-d^2)^2), applied twice as in ref
    csr_cv[pr] = make_int2(c, __float_as_int(dw * dinv[r] * dinv[c]));
    int pc = offs_c[c] + atomicAdd(&cnt_c[c], 1);
    csr_row[pc] = r;
  }
}

// ---------------- fused GCN layer: float4 group-gather + GEMV + leaky + rownorm ------------
// Lane = (grp, pos): grp = lane>>4 (4 groups), pos = lane&15. One gather instruction
// covers 4 neighbor rows (1KiB) instead of 1 (256B). 4-wide unroll keeps VGPR < 128.
// 512-thread blocks: 8 waves share one 32KB weight-LDS copy -> 4 blocks = 32 waves/CU.
__global__ __launch_bounds__(512) void k_gcn2(const int* __restrict__ offs,
                      const int2* __restrict__ csr_cv,
                      const float* __restrict__ gfeat,
                      const float* __restrict__ W0, const float* __restrict__ W1,
                      float* __restrict__ out, int N){
  __shared__ float lw0[4096], lw1[4096];
  for (int i = threadIdx.x; i < 4096; i += 512){ lw0[i] = W0[i]; lw1[i] = W1[i]; }
  __syncthreads();
  int lane = threadIdx.x & 63, wave = threadIdx.x >> 6;
  int grp = lane >> 4, pos = lane & 15;
  const float4* gf4 = (const float4*)gfeat;
  int wgl = blockIdx.x * 8 + wave;
  int nw = gridDim.x * 8;
  for (int r = wgl; r < N; r += nw){
    int j0 = offs[r], j1 = offs[r + 1];
    float4 s4 = {0.f, 0.f, 0.f, 0.f};
    for (int jb = j0; jb < j1; jb += 64){
      int rem = j1 - jb;
      int cnt = rem < 64 ? rem : 64;
      int jj = jb + lane;
      int2 cv = make_int2(0, 0);
      if (jj < j1) cv = csr_cv[jj];                 // coalesced 8B chunk load
      int myc = cv.x; float myv = __int_as_float(cv.y);  // myv==0 beyond cnt
      int rounds = (cnt + 3) >> 2;                  // 4 edges per round (1/group)
      int kk = 0;
      for (; kk + 4 <= rounds; kk += 4){
        int e0 = (kk+0)*4 + grp, e1 = (kk+1)*4 + grp,
            e2 = (kk+2)*4 + grp, e3 = (kk+3)*4 + grp;
        int   c0 = __shfl(myc, e0, 64), c1 = __shfl(myc, e1, 64),
              c2 = __shfl(myc, e2, 64), c3 = __shfl(myc, e3, 64);
        float v0 = __shfl(myv, e0, 64), v1 = __shfl(myv, e1, 64),
              v2 = __shfl(myv, e2, 64), v3 = __shfl(myv, e3, 64);
        float4 f0 = gf4[(long)c0 * 16 + pos];
        float4 f1 = gf4[(long)c1 * 16 + pos];
        float4 f2 = gf4[(long)c2 * 16 + pos];
        float4 f3 = gf4[(long)c3 * 16 + pos];
        s4.x += v0*f0.x; s4.y += v0*f0.y; s4.z += v0*f0.z; s4.w += v0*f0.w;
        s4.x += v1*f1.x; s4.y += v1*f1.y; s4.z += v1*f1.z; s4.w += v1*f1.w;
        s4.x += v2*f2.x; s4.y += v2*f2.y; s4.z += v2*f2.z; s4.w += v2*f2.w;
        s4.x += v3*f3.x; s4.y += v3*f3.y; s4.z += v3*f3.z; s4.w += v3*f3.w;
      }
      for (; kk < rounds; kk++){
        int e = kk*4 + grp;
        int c = __shfl(myc, e, 64);
        float v = __shfl(myv, e, 64);
        float4 f = gf4[(long)c * 16 + pos];
        s4.x += v*f.x; s4.y += v*f.y; s4.z += v*f.z; s4.w += v*f.w;
      }
    }
    // reduce across the 4 groups (lanes differing in bits 4,5)
    #pragma unroll
    for (int m = 16; m <= 32; m <<= 1){
      s4.x += __shfl_xor(s4.x, m, 64);
      s4.y += __shfl_xor(s4.y, m, 64);
      s4.z += __shfl_xor(s4.z, m, 64);
      s4.w += __shfl_xor(s4.w, m, 64);
    }
    // redistribute: lane l wants dim l = component (l&3) of pos-lane (l>>2)
    int src = lane >> 2, cc = lane & 3;
    float sx = __shfl(s4.x, src, 64);
    float sy = __shfl(s4.y, src, 64);
    float sz = __shfl(s4.z, src, 64);
    float sw = __shfl(s4.w, src, 64);
    float s = (cc == 0) ? sx : (cc == 1) ? sy : (cc == 2) ? sz : sw;

    float g = gfeat[(long)r * 64 + lane];
    float acc = 0.f;
    #pragma unroll
    for (int k = 0; k < 64; k++){
      float sk = __shfl(s, k, 64);
      float gk = __shfl(g, k, 64);
      acc += sk * lw0[k * 64 + lane] + gk * sk * lw1[k * 64 + lane];
    }
    float x = leakyf(acc);
    float nrm = sqrtf(wred(x * x));
    out[(long)r * 64 + lane] = x / fmaxf(nrm, 1e-12f);
  }
}

// ---------------- neighbor pooling: float4 group-gather + mean ----------------
__global__ __launch_bounds__(256) void k_pool_gather(const int* __restrict__ offs,
                      const int* __restrict__ csr_row,
                      const float* __restrict__ poi, float* __restrict__ neigh, int N){
  int lane = threadIdx.x & 63, wave = threadIdx.x >> 6;
  int grp = lane >> 4, pos = lane & 15;
  const float4* poi4 = (const float4*)poi;
  int wgl = blockIdx.x * 4 + wave;
  int nw = gridDim.x * 4;
  for (int n = wgl; n < N; n += nw){
    int j0 = offs[n], j1 = offs[n + 1];
    float4 s4 = {0.f, 0.f, 0.f, 0.f};
    for (int jb = j0; jb < j1; jb += 64){
      int rem = j1 - jb;
      int cnt = rem < 64 ? rem : 64;
      int jj = jb + lane;
      int myc = 0; float myw = 0.f;
      if (jj < j1){ myc = csr_row[jj]; myw = 1.f; }
      int rounds = (cnt + 3) >> 2;
      int kk = 0;
      for (; kk + 4 <= rounds; kk += 4){
        int e0 = (kk+0)*4 + grp, e1 = (kk+1)*4 + grp,
            e2 = (kk+2)*4 + grp, e3 = (kk+3)*4 + grp;
        int   c0 = __shfl(myc, e0, 64), c1 = __shfl(myc, e1, 64),
              c2 = __shfl(myc, e2, 64), c3 = __shfl(myc, e3, 64);
        float v0 = __shfl(myw, e0, 64), v1 = __shfl(myw, e1, 64),
              v2 = __shfl(myw, e2, 64), v3 = __shfl(myw, e3, 64);
        float4 f0 = poi4[(long)c0 * 16 + pos];
        float4 f1 = poi4[(long)c1 * 16 + pos];
        float4 f2 = poi4[(long)c2 * 16 + pos];
        float4 f3 = poi4[(long)c3 * 16 + pos];
        s4.x += v0*f0.x; s4.y += v0*f0.y; s4.z += v0*f0.z; s4.w += v0*f0.w;
        s4.x += v1*f1.x; s4.y += v1*f1.y; s4.z += v1*f1.z; s4.w += v1*f1.w;
        s4.x += v2*f2.x; s4.y += v2*f2.y; s4.z += v2*f2.z; s4.w += v2*f2.w;
        s4.x += v3*f3.x; s4.y += v3*f3.y; s4.z += v3*f3.z; s4.w += v3*f3.w;
      }
      for (; kk < rounds; kk++){
        int e = kk*4 + grp;
        int c = __shfl(myc, e, 64);
        float v = __shfl(myw, e, 64);
        float4 f = poi4[(long)c * 16 + pos];
        s4.x += v*f.x; s4.y += v*f.y; s4.z += v*f.z; s4.w += v*f.w;
      }
    }
    #pragma unroll
    for (int m = 16; m <= 32; m <<= 1){
      s4.x += __shfl_xor(s4.x, m, 64);
      s4.y += __shfl_xor(s4.y, m, 64);
      s4.z += __shfl_xor(s4.z, m, 64);
      s4.w += __shfl_xor(s4.w, m, 64);
    }
    int src = lane >> 2, cc = lane & 3;
    float sx = __shfl(s4.x, src, 64);
    float sy = __shfl(s4.y, src, 64);
    float sz = __shfl(s4.z, src, 64);
    float sw = __shfl(s4.w, src, 64);
    float s = (cc == 0) ? sx : (cc == 1) ? sy : (cc == 2) ? sz : sw;
    float inv = 1.f / fmaxf((float)(j1 - j0), 1.f);
    neigh[(long)n * 64 + lane] = s * inv;
  }
}

// ---------------- generic [M,64]@[64,64] (+bias), optional row gather ----------------
template<bool GATHER>
__global__ __launch_bounds__(256) void k_gemm64(const float* __restrict__ X, const int* __restrict__ ridx,
                         const float* __restrict__ W, const float* __restrict__ bias,
                         float* __restrict__ Y, int M){
  __shared__ float lw[4096];
  for (int i = threadIdx.x; i < 4096; i += 256) lw[i] = W[i];
  __syncthreads();
  int lane = threadIdx.x & 63, wave = threadIdx.x >> 6;
  int wgl = blockIdx.x * 4 + wave;
  int nw = gridDim.x * 4;
  for (int r = wgl; r < M; r += nw){
    long src = GATHER ? (long)ridx[r] : (long)r;
    float x = X[src * 64 + lane];
    float acc = bias ? bias[lane] : 0.f;
    #pragma unroll
    for (int k = 0; k < 64; k++) acc += __shfl(x, k, 64) * lw[k * 64 + lane];
    Y[(long)r * 64 + lane] = acc;
  }
}

// ---------------- seq_query: per-batch attention + contiguous segment sum ----------------
// hq = q@W1 + b1 + b2 hoisted out of the per-position loop (q fixed per block).
template<bool GATHER_S>
__global__ __launch_bounds__(256) void k_seqq(const float* __restrict__ sbase, const int* __restrict__ sidx,
                       const float* __restrict__ qbase, const int* __restrict__ tar,
                       const float* __restrict__ W1, const float* __restrict__ b1,
                       const float* __restrict__ W2, const float* __restrict__ b2,
                       const float* __restrict__ a, const float* __restrict__ ab,
                       float* __restrict__ out, int L){
  __shared__ float lw1[4096], lw2[4096], la[64], lb[64];
  __shared__ float red[4][64];
  int tid = threadIdx.x;
  for (int i = tid; i < 4096; i += 256){ lw1[i] = W1[i]; lw2[i] = W2[i]; }
  if (tid < 64){ la[tid] = a[tid]; lb[tid] = b1[tid] + b2[tid]; }
  __syncthreads();
  int lane = tid & 63, wave = tid >> 6;
  int b = blockIdx.x;
  float q = qbase[(long)tar[b] * 64 + lane];
  float ab0 = ab[0];
  float hq = lb[lane];
  #pragma unroll
  for (int k = 0; k < 64; k++) hq += __shfl(q, k, 64) * lw1[k * 64 + lane];
  float acc = 0.f;
  for (int tl = wave; tl < L; tl += 4){
    int t = b * L + tl;
    long srow = GATHER_S ? (long)sidx[t] : (long)t;
    float s = sbase[srow * 64 + lane];
    float h = hq;
    #pragma unroll
    for (int k = 0; k < 64; k++) h += __shfl(s, k, 64) * lw2[k * 64 + lane];
    float sg = sigmf(h);
    float w = wred(sg * la[lane]) + ab0;
    acc += w * s;
  }
  red[wave][lane] = acc;
  __syncthreads();
  if (tid < 64)
    out[(long)b * 64 + tid] = red[0][tid] + red[1][tid] + red[2][tid] + red[3][tid];
}

// ---------------- per-batch mean pools (two sources, same indices) ----------------
__global__ __launch_bounds__(256) void k_pool(const float* __restrict__ neigh, const float* __restrict__ poi,
                       const int* __restrict__ sidx, float* __restrict__ p1,
                       float* __restrict__ p2, int L){
  __shared__ float r1[4][64], r2[4][64];
  int tid = threadIdx.x, lane = tid & 63, wave = tid >> 6, b = blockIdx.x;
  float a1 = 0.f, a2 = 0.f;
  for (int tl = wave; tl < L; tl += 4){
    long idx = sidx[b * L + tl];
    a1 += neigh[idx * 64 + lane];
    a2 += poi[idx * 64 + lane];
  }
  r1[wave][lane] = a1; r2[wave][lane] = a2;
  __syncthreads();
  float inv = 1.f / (float)L;
  if (tid < 64){
    p1[(long)b * 64 + tid] = (r1[0][tid] + r1[1][tid] + r1[2][tid] + r1[3][tid]) * inv;
    p2[(long)b * 64 + tid] = (r2[0][tid] + r2[1][tid] + r2[2][tid] + r2[3][tid]) * inv;
  }
}

// ---------------- GGC message scatter over T session edges ----------------
__global__ void k_edge_scatter(const int* __restrict__ e0, const int* __restrict__ e1,
                               const float* __restrict__ hw, float* __restrict__ m, int T){
  long gid = (long)blockIdx.x * blockDim.x + threadIdx.x;
  if (gid >= (long)T * 64) return;
  int e = (int)(gid >> 6), c = (int)(gid & 63);
  atomicAdd(&m[(long)e1[e] * 64 + c], hw[(long)e0[e] * 64 + c]);
}

// ---------------- GRU split, spill-free: gi = m @ wih^T + bih ----------------
__global__ __launch_bounds__(256) void k_gi(const float* __restrict__ m,
                     const float* __restrict__ wih, const float* __restrict__ bih,
                     float* __restrict__ gi, int T){
  __shared__ float lw[64 * 193];
  __shared__ float lb[192];
  int tid = threadIdx.x, lane = tid & 63, wave = tid >> 6;
  if (tid < 192) lb[tid] = bih[tid];
  for (int idx = tid; idx < 192 * 64; idx += 256){
    int j = idx >> 6, k = idx & 63;
    lw[k * 193 + j] = wih[idx];          // transposed + padded: conflict-free both ways
  }
  __syncthreads();
  int r0 = blockIdx.x * 4 + wave, nw = gridDim.x * 4;
  for (int t = r0; t < T; t += nw){
    float x = m[(long)t * 64 + lane];
    float a0 = lb[lane], a1 = lb[64 + lane], a2 = lb[128 + lane];
    #pragma unroll
    for (int k = 0; k < 64; k++){
      float xk = __shfl(x, k, 64);
      a0 += xk * lw[k * 193 + lane];
      a1 += xk * lw[k * 193 + 64 + lane];
      a2 += xk * lw[k * 193 + 128 + lane];
    }
    gi[(long)t * 192 + lane] = a0;
    gi[(long)t * 192 + 64 + lane] = a1;
    gi[(long)t * 192 + 128 + lane] = a2;
  }
}

// ---------------- GRU part 2: gh on the fly + fused gate math ----------------
__global__ __launch_bounds__(256) void k_gru2(const float* __restrict__ gi,
                       const float* __restrict__ poi, const int* __restrict__ sidx,
                       const float* __restrict__ whh, const float* __restrict__ bhh,
                       float* __restrict__ out, int T){
  __shared__ float lw[64 * 193];
  __shared__ float lb[192];
  int tid = threadIdx.x, lane = tid & 63, wave = tid >> 6;
  if (tid < 192) lb[tid] = bhh[tid];
  for (int idx = tid; idx < 192 * 64; idx += 256){
    int j = idx >> 6, k = idx & 63;
    lw[k * 193 + j] = whh[idx];
  }
  __syncthreads();
  int r0 = blockIdx.x * 4 + wave, nw = gridDim.x * 4;
  for (int t = r0; t < T; t += nw){
    float h = poi[(long)sidx[t] * 64 + lane];
    float b0 = lb[lane], b1 = lb[64 + lane], b2 = lb[128 + lane];
    #pragma unroll
    for (int k = 0; k < 64; k++){
      float hk = __shfl(h, k, 64);
      b0 += hk * lw[k * 193 + lane];
      b1 += hk * lw[k * 193 + 64 + lane];
      b2 += hk * lw[k * 193 + 128 + lane];
    }
    float r = sigmf(gi[(long)t * 192 + lane] + b0);
    float z = sigmf(gi[(long)t * 192 + 64 + lane] + b1);
    float n = tanhf(gi[(long)t * 192 + 128 + lane] + r * b2);   // n = tanh(i_n + r*h_n)
    float nh = (1.f - z) * n + z * h;
    out[(long)t * 64 + lane] = leakyf(nh);
  }
}

// ---------------- final head: con_loss, MLP logits, passthrough outputs ----------------
__global__ __launch_bounds__(64) void k_final(
    const float* __restrict__ poi, const float* __restrict__ gf,
    const int* __restrict__ tar,
    const float* __restrict__ geo_enc, const float* __restrict__ sess_enc,
    const float* __restrict__ gpool, const float* __restrict__ spool,
    const float* __restrict__ mW1, const float* __restrict__ mb1,
    const float* __restrict__ mW2, const float* __restrict__ mb2,
    const float* __restrict__ y, float* __restrict__ out, int B){
  int b = blockIdx.x, c = threadIdx.x;
  long tp = tar[b];
  long offT = 3L * B, offG = 3L * B + (long)B * 64;
  long offGP = 3L * B + 2L * B * 64, offSP = 3L * B + 3L * B * 64;
  float f0 = poi[tp * 64 + c];
  float f1 = gf[tp * 64 + c];
  float f2 = out[offSP + (long)b * 64 + c];   // sess_enc_p (already written)
  float f3 = out[offGP + (long)b * 64 + c];   // geo_enc_p
  float ge = geo_enc[(long)b * 64 + c], se = sess_enc[(long)b * 64 + c];
  float gp = gpool[(long)b * 64 + c], sp = spool[(long)b * 64 + c];
  float d1 = wred(ge * sp);
  float d2 = wred(ge * gp);
  float d3 = wred(se * gp);
  float d4 = wred(se * sp);
  float con = softplusf(d1 - d2) + softplusf(d3 - d4);
  float acc = mb1[c];
  #pragma unroll
  for (int k = 0; k < 64; k++){
    acc += __shfl(f0, k, 64) * mW1[k * 64 + c];
    acc += __shfl(f1, k, 64) * mW1[(64 + k) * 64 + c];
    acc += __shfl(f2, k, 64) * mW1[(128 + k) * 64 + c];
    acc += __shfl(f3, k, 64) * mW1[(192 + k) * 64 + c];
  }
  float hid = leakyf(acc);
  float lsum = wred(hid * mW2[c]);
  if (c == 0){
    out[b] = lsum + mb2[0];
    out[B + b] = con;
    out[2L * B + b] = y[b];
  }
  out[offT + (long)b * 64 + c] = f0;
  out[offG + (long)b * 64 + c] = f1;
}

extern "C" void kernel_launch(void* const* d_in, const int* in_sizes, int n_in,
                              void* d_out, int out_size, void* d_ws, size_t ws_size,
                              hipStream_t stream){
  const int*   sess_idx = (const int*)d_in[0];
  const int*   edges    = (const int*)d_in[1];
  const int*   tar_poi  = (const int*)d_in[3];
  const float* y        = (const float*)d_in[4];
  const int*   eidx     = (const int*)d_in[5];
  const float* dist     = (const float*)d_in[6];
  const float* poi      = (const float*)d_in[7];
  const float* geoW0    = (const float*)d_in[8];
  const float* geoW1    = (const float*)d_in[9];
  const float* ggcW     = (const float*)d_in[10];
  const float* wih      = (const float*)d_in[11];
  const float* whh      = (const float*)d_in[12];
  const float* bih      = (const float*)d_in[13];
  const float* bhh      = (const float*)d_in[14];
  const float* geoqW1   = (const float*)d_in[15];
  const float* geoqb1   = (const float*)d_in[16];
  const float* geoqW2   = (const float*)d_in[17];
  const float* geoqb2   = (const float*)d_in[18];
  const float* geoqa    = (const float*)d_in[19];
  const float* geoqab   = (const float*)d_in[20];
  const float* sessqW1  = (const float*)d_in[21];
  const float* sessqb1  = (const float*)d_in[22];
  const float* sessqW2  = (const float*)d_in[23];
  const float* sessqb2  = (const float*)d_in[24];
  const float* sessqa   = (const float*)d_in[25];
  const float* sessqab  = (const float*)d_in[26];
  const float* geo_proj = (const float*)d_in[27];
  const float* sess_proj= (const float*)d_in[28];
  const float* mW1      = (const float*)d_in[29];
  const float* mb1      = (const float*)d_in[30];
  const float* mW2      = (const float*)d_in[31];
  const float* mb2      = (const float*)d_in[32];

  const int T = in_sizes[0];
  const int B = in_sizes[3];
  const int E = in_sizes[5] / 2;
  const int N = in_sizes[7] / 64;
  const int G = in_sizes[8] / 4096;
  const int L = T / B;
  const int* erow = eidx;
  const int* ecol = eidx + E;
  const int* e0 = edges;
  const int* e1 = edges + T;

  // workspace carve-out (256B aligned).
  // gi (T*192 floats = 25.2MB) aliases gf0+csr_cv (26MB, dead post-GCN).
  // poolbuf serves as neigh (pooling) then mbuf (GGC); sessh aliases hw
  // (hw dead after k_edge_scatter, sessh written later by k_gru2).
  // Total ≈ 68 MB.
  char* w = (char*)d_ws;
  size_t off = 0;
  auto nxt = [&](size_t bytes)->void*{
    void* p = w + off; off = (off + bytes + 255) & ~(size_t)255; return p;
  };
  int*   deg_row = (int*)  nxt((size_t)N * 4);          // reused as cnt_row
  int*   deg_col = (int*)  nxt((size_t)N * 4);          // reused as cnt_col
  int*   offs_r  = (int*)  nxt((size_t)(N + 1) * 4);
  int*   offs_c  = (int*)  nxt((size_t)(N + 1) * 4);
  float* dinv    = (float*)nxt((size_t)N * 4);
  float* gf1     = (float*)nxt((size_t)N * 256);        // final geo_feat lands here
  float* geo_enc = (float*)nxt((size_t)B * 256);
  float* sess_enc= (float*)nxt((size_t)B * 256);
  float* p1      = (float*)nxt((size_t)B * 256);
  float* p2      = (float*)nxt((size_t)B * 256);
  float* gpool   = (float*)nxt((size_t)B * 256);
  float* spool   = (float*)nxt((size_t)B * 256);
  float* gf0     = (float*)nxt((size_t)N * 256);        // ┐
  int2*  csr_cv  = (int2*) nxt((size_t)E * 8);          // ┘ gi aliases this span (26MB>=25.2MB)
  int*   csr_row = (int*)  nxt((size_t)E * 4);
  float* poolbuf = (float*)nxt((size_t)N * 256);        // neigh, then mbuf (T*256 <= N*256)
  float* hw      = (float*)nxt((size_t)T * 256);        // then sessh
  float* gi      = gf0;
  float* neigh   = poolbuf;
  float* mbuf    = poolbuf;
  float* sessh   = hw;
  float* outf    = (float*)d_out;

  const long offGP = 3L * B + 2L * B * 64;
  const long offSP = 3L * B + 3L * B * 64;

  // 1. degrees -> offsets (+dinv) -> fused CSR fill
  hipMemsetAsync(deg_row, 0, (size_t)N * 4, stream);
  hipMemsetAsync(deg_col, 0, (size_t)N * 4, stream);
  k_deg2<<<CDIV(E,256),256,0,stream>>>(erow, ecol, deg_row, deg_col, E);
  k_scan2<<<2,1024,0,stream>>>(deg_row, offs_r, deg_col, offs_c, dinv, N);
  hipMemsetAsync(deg_row, 0, (size_t)N * 4, stream);    // reuse as fill counters
  hipMemsetAsync(deg_col, 0, (size_t)N * 4, stream);
  k_fill2<<<CDIV(E,256),256,0,stream>>>(erow, ecol, dist, dinv,
                                        offs_r, deg_row, csr_cv,
                                        offs_c, deg_col, csr_row, E);

  // 2. Geo-GCN layers, gather form (ping-pong so final layer lands in gf1)
  const float* cur = poi;
  float* nextb = (G & 1) ? gf1 : gf0;
  for (int g = 0; g < G; g++){
    k_gcn2<<<1024,512,0,stream>>>(offs_r, csr_cv, cur,
                                  geoW0 + (size_t)g * 4096, geoW1 + (size_t)g * 4096,
                                  nextb, N);
    cur = nextb;
    nextb = (nextb == gf0) ? gf1 : gf0;
  }
  const float* gf = cur;   // == gf1

  // 3. seq_query (geo) -> geo_enc ; projection -> out geo_enc_p
  k_seqq<true><<<B,256,0,stream>>>(gf, sess_idx, gf, tar_poi,
                                   geoqW1, geoqb1, geoqW2, geoqb2, geoqa, geoqab,
                                   geo_enc, L);
  k_gemm64<false><<<CDIV(B,4),256,0,stream>>>(geo_enc, nullptr, geo_proj, nullptr,
                                              outf + offGP, B);

  // 4. neighbor pooling, gather form (mean fused via offsets)
  k_pool_gather<<<2048,256,0,stream>>>(offs_c, csr_row, poi, neigh, N);
  k_pool<<<B,256,0,stream>>>(neigh, poi, sess_idx, p1, p2, L);
  k_gemm64<false><<<CDIV(B,4),256,0,stream>>>(p1, nullptr, geo_proj, nullptr, gpool, B);
  k_gemm64<false><<<CDIV(B,4),256,0,stream>>>(p2, nullptr, sess_proj, nullptr, spool, B);

  // 5. GatedGraphConv + GRU (poolbuf becomes mbuf; gi aliases gf0+csr_cv)
  k_gemm64<true><<<2048,256,0,stream>>>(poi, sess_idx, ggcW, nullptr, hw, T);
  hipMemsetAsync(mbuf, 0, (size_t)T * 256, stream);
  k_edge_scatter<<<(int)CDIV((long)T*64,256),256,0,stream>>>(e0, e1, hw, mbuf, T);
  k_gi<<<1024,256,0,stream>>>(mbuf, wih, bih, gi, T);
  k_gru2<<<1024,256,0,stream>>>(gi, poi, sess_idx, whh, bhh, sessh, T);

  // 6. seq_query (sess) -> sess_enc ; projection -> out sess_enc_p
  k_seqq<false><<<B,256,0,stream>>>(sessh, nullptr, poi, tar_poi,
                                    sessqW1, sessqb1, sessqW2, sessqb2, sessqa, sessqab,
                                    sess_enc, L);
  k_gemm64<false><<<CDIV(B,4),256,0,stream>>>(sess_enc, nullptr, sess_proj, nullptr,
                                              outf + offSP, B);

  // 7. final head
  k_final<<<B,64,0,stream>>>(poi, gf, tar_poi, geo_enc, sess_enc, gpool, spool,
                             mW1, mb1, mW2, mb2, y, outf, B);
}

// Round 10
// 821.776 us; speedup vs baseline: 1.5638x; 1.1502x over previous
//
#include <hip/hip_runtime.h>
#include <math.h>

#define CDIV(a,b) (((a)+(b)-1)/(b))

__device__ __forceinline__ float wred(float v){
  #pragma unroll
  for (int o = 32; o; o >>= 1) v += __shfl_xor(v, o, 64);
  return v;
}
__device__ __forceinline__ float leakyf(float x){ return x > 0.f ? x : 0.01f * x; }
__device__ __forceinline__ float sigmf(float x){ return 1.f / (1.f + expf(-x)); }
__device__ __forceinline__ float softplusf(float x){
  return fmaxf(x, 0.f) + log1pf(expf(-fabsf(x)));
}

// ---------------- degrees (both axes) + per-edge rank capture ----------------
__global__ void k_deg2(const int* __restrict__ row, const int* __restrict__ col,
                       int* __restrict__ deg_row, int* __restrict__ deg_col,
                       int* __restrict__ rank_r, int* __restrict__ rank_c, int E){
  int e = blockIdx.x * blockDim.x + threadIdx.x;
  if (e < E){
    rank_r[e] = atomicAdd(&deg_row[row[e]], 1);
    rank_c[e] = atomicAdd(&deg_col[col[e]], 1);
  }
}

// ---------------- exclusive scan of two N-arrays; block 1 also emits dinv ----------------
__global__ __launch_bounds__(1024) void k_scan2(const int* __restrict__ in0, int* __restrict__ out0,
                        const int* __restrict__ in1, int* __restrict__ out1,
                        float* __restrict__ dinv, int n){
  __shared__ int wincl[16];
  const int* in  = blockIdx.x ? in1 : in0;
  int* out       = blockIdx.x ? out1 : out0;
  int tid = threadIdx.x, lane = tid & 63, wv = tid >> 6;
  int carry = 0;
  for (int base = 0; base < n; base += 1024){
    int i = base + tid;
    int x = (i < n) ? in[i] : 0;
    int v = x;
    #pragma unroll
    for (int ofs = 1; ofs < 64; ofs <<= 1){
      int t = __shfl_up(v, ofs, 64);
      if (lane >= ofs) v += t;
    }
    if (lane == 63) wincl[wv] = v;
    __syncthreads();
    if (wv == 0 && lane < 16){
      int s = wincl[lane];
      #pragma unroll
      for (int ofs = 1; ofs < 16; ofs <<= 1){
        int t = __shfl_up(s, ofs, 64);
        if (lane >= ofs) s += t;
      }
      wincl[lane] = s;
    }
    __syncthreads();
    int woff = wv ? wincl[wv - 1] : 0;
    if (i < n) out[i] = carry + woff + v - x;   // exclusive
    carry += wincl[15];
    __syncthreads();
  }
  if (tid == 0) out[n] = carry;
  if (blockIdx.x == 1){
    for (int i = tid; i < n; i += 1024){
      int d = in1[i];
      dinv[i] = d > 0 ? 1.f / sqrtf((float)d) : 0.f;
    }
  }
}

// ---------------- CSR fill, atomic-free: pos = offs[node] + precaptured rank ----------------
__global__ void k_fill2(const int* __restrict__ row, const int* __restrict__ col,
                        const float* __restrict__ dist, const float* __restrict__ dinv,
                        const int* __restrict__ offs_r, const int* __restrict__ rank_r,
                        int2* __restrict__ csr_cv,
                        const int* __restrict__ offs_c, const int* __restrict__ rank_c,
                        int* __restrict__ csr_row, int E){
  int e = blockIdx.x * blockDim.x + threadIdx.x;
  if (e < E){
    int r = row[e], c = col[e];
    int pr = offs_r[r] + rank_r[e];
    float d = dist[e];
    float t = expf(-d * d);
    float dw = expf(-t * t);            // exp(-exp(-d^2)^2), applied twice as in ref
    csr_cv[pr] = make_int2(c, __float_as_int(dw * dinv[r] * dinv[c]));
    int pc = offs_c[c] + rank_c[e];
    csr_row[pc] = r;
  }
}

// ---------------- fused GCN layer: float4 group-gather + GEMV + leaky + rownorm ------------
// Lane = (grp, pos): grp = lane>>4 (4 groups), pos = lane&15. One gather instruction
// covers 4 neighbor rows (1KiB) instead of 1 (256B). 4-wide unroll keeps VGPR < 128.
// 512-thread blocks: 8 waves share one 32KB weight-LDS copy -> 4 blocks = 32 waves/CU.
__global__ __launch_bounds__(512) void k_gcn2(const int* __restrict__ offs,
                      const int2* __restrict__ csr_cv,
                      const float* __restrict__ gfeat,
                      const float* __restrict__ W0, const float* __restrict__ W1,
                      float* __restrict__ out, int N){
  __shared__ float lw0[4096], lw1[4096];
  for (int i = threadIdx.x; i < 4096; i += 512){ lw0[i] = W0[i]; lw1[i] = W1[i]; }
  __syncthreads();
  int lane = threadIdx.x & 63, wave = threadIdx.x >> 6;
  int grp = lane >> 4, pos = lane & 15;
  const float4* gf4 = (const float4*)gfeat;
  int wgl = blockIdx.x * 8 + wave;
  int nw = gridDim.x * 8;
  for (int r = wgl; r < N; r += nw){
    int j0 = offs[r], j1 = offs[r + 1];
    float4 s4 = {0.f, 0.f, 0.f, 0.f};
    for (int jb = j0; jb < j1; jb += 64){
      int rem = j1 - jb;
      int cnt = rem < 64 ? rem : 64;
      int jj = jb + lane;
      int2 cv = make_int2(0, 0);
      if (jj < j1) cv = csr_cv[jj];                 // coalesced 8B chunk load
      int myc = cv.x; float myv = __int_as_float(cv.y);  // myv==0 beyond cnt
      int rounds = (cnt + 3) >> 2;                  // 4 edges per round (1/group)
      int kk = 0;
      for (; kk + 4 <= rounds; kk += 4){
        int e0 = (kk+0)*4 + grp, e1 = (kk+1)*4 + grp,
            e2 = (kk+2)*4 + grp, e3 = (kk+3)*4 + grp;
        int   c0 = __shfl(myc, e0, 64), c1 = __shfl(myc, e1, 64),
              c2 = __shfl(myc, e2, 64), c3 = __shfl(myc, e3, 64);
        float v0 = __shfl(myv, e0, 64), v1 = __shfl(myv, e1, 64),
              v2 = __shfl(myv, e2, 64), v3 = __shfl(myv, e3, 64);
        float4 f0 = gf4[(long)c0 * 16 + pos];
        float4 f1 = gf4[(long)c1 * 16 + pos];
        float4 f2 = gf4[(long)c2 * 16 + pos];
        float4 f3 = gf4[(long)c3 * 16 + pos];
        s4.x += v0*f0.x; s4.y += v0*f0.y; s4.z += v0*f0.z; s4.w += v0*f0.w;
        s4.x += v1*f1.x; s4.y += v1*f1.y; s4.z += v1*f1.z; s4.w += v1*f1.w;
        s4.x += v2*f2.x; s4.y += v2*f2.y; s4.z += v2*f2.z; s4.w += v2*f2.w;
        s4.x += v3*f3.x; s4.y += v3*f3.y; s4.z += v3*f3.z; s4.w += v3*f3.w;
      }
      for (; kk < rounds; kk++){
        int e = kk*4 + grp;
        int c = __shfl(myc, e, 64);
        float v = __shfl(myv, e, 64);
        float4 f = gf4[(long)c * 16 + pos];
        s4.x += v*f.x; s4.y += v*f.y; s4.z += v*f.z; s4.w += v*f.w;
      }
    }
    // reduce across the 4 groups (lanes differing in bits 4,5)
    #pragma unroll
    for (int m = 16; m <= 32; m <<= 1){
      s4.x += __shfl_xor(s4.x, m, 64);
      s4.y += __shfl_xor(s4.y, m, 64);
      s4.z += __shfl_xor(s4.z, m, 64);
      s4.w += __shfl_xor(s4.w, m, 64);
    }
    // redistribute: lane l wants dim l = component (l&3) of pos-lane (l>>2)
    int src = lane >> 2, cc = lane & 3;
    float sx = __shfl(s4.x, src, 64);
    float sy = __shfl(s4.y, src, 64);
    float sz = __shfl(s4.z, src, 64);
    float sw = __shfl(s4.w, src, 64);
    float s = (cc == 0) ? sx : (cc == 1) ? sy : (cc == 2) ? sz : sw;

    float g = gfeat[(long)r * 64 + lane];
    float acc = 0.f;
    #pragma unroll
    for (int k = 0; k < 64; k++){
      float sk = __shfl(s, k, 64);
      float gk = __shfl(g, k, 64);
      acc += sk * lw0[k * 64 + lane] + gk * sk * lw1[k * 64 + lane];
    }
    float x = leakyf(acc);
    float nrm = sqrtf(wred(x * x));
    out[(long)r * 64 + lane] = x / fmaxf(nrm, 1e-12f);
  }
}

// ---------------- neighbor pooling: float4 group-gather + mean ----------------
__global__ __launch_bounds__(256) void k_pool_gather(const int* __restrict__ offs,
                      const int* __restrict__ csr_row,
                      const float* __restrict__ poi, float* __restrict__ neigh, int N){
  int lane = threadIdx.x & 63, wave = threadIdx.x >> 6;
  int grp = lane >> 4, pos = lane & 15;
  const float4* poi4 = (const float4*)poi;
  int wgl = blockIdx.x * 4 + wave;
  int nw = gridDim.x * 4;
  for (int n = wgl; n < N; n += nw){
    int j0 = offs[n], j1 = offs[n + 1];
    float4 s4 = {0.f, 0.f, 0.f, 0.f};
    for (int jb = j0; jb < j1; jb += 64){
      int rem = j1 - jb;
      int cnt = rem < 64 ? rem : 64;
      int jj = jb + lane;
      int myc = 0; float myw = 0.f;
      if (jj < j1){ myc = csr_row[jj]; myw = 1.f; }
      int rounds = (cnt + 3) >> 2;
      int kk = 0;
      for (; kk + 4 <= rounds; kk += 4){
        int e0 = (kk+0)*4 + grp, e1 = (kk+1)*4 + grp,
            e2 = (kk+2)*4 + grp, e3 = (kk+3)*4 + grp;
        int   c0 = __shfl(myc, e0, 64), c1 = __shfl(myc, e1, 64),
              c2 = __shfl(myc, e2, 64), c3 = __shfl(myc, e3, 64);
        float v0 = __shfl(myw, e0, 64), v1 = __shfl(myw, e1, 64),
              v2 = __shfl(myw, e2, 64), v3 = __shfl(myw, e3, 64);
        float4 f0 = poi4[(long)c0 * 16 + pos];
        float4 f1 = poi4[(long)c1 * 16 + pos];
        float4 f2 = poi4[(long)c2 * 16 + pos];
        float4 f3 = poi4[(long)c3 * 16 + pos];
        s4.x += v0*f0.x; s4.y += v0*f0.y; s4.z += v0*f0.z; s4.w += v0*f0.w;
        s4.x += v1*f1.x; s4.y += v1*f1.y; s4.z += v1*f1.z; s4.w += v1*f1.w;
        s4.x += v2*f2.x; s4.y += v2*f2.y; s4.z += v2*f2.z; s4.w += v2*f2.w;
        s4.x += v3*f3.x; s4.y += v3*f3.y; s4.z += v3*f3.z; s4.w += v3*f3.w;
      }
      for (; kk < rounds; kk++){
        int e = kk*4 + grp;
        int c = __shfl(myc, e, 64);
        float v = __shfl(myw, e, 64);
        float4 f = poi4[(long)c * 16 + pos];
        s4.x += v*f.x; s4.y += v*f.y; s4.z += v*f.z; s4.w += v*f.w;
      }
    }
    #pragma unroll
    for (int m = 16; m <= 32; m <<= 1){
      s4.x += __shfl_xor(s4.x, m, 64);
      s4.y += __shfl_xor(s4.y, m, 64);
      s4.z += __shfl_xor(s4.z, m, 64);
      s4.w += __shfl_xor(s4.w, m, 64);
    }
    int src = lane >> 2, cc = lane & 3;
    float sx = __shfl(s4.x, src, 64);
    float sy = __shfl(s4.y, src, 64);
    float sz = __shfl(s4.z, src, 64);
    float sw = __shfl(s4.w, src, 64);
    float s = (cc == 0) ? sx : (cc == 1) ? sy : (cc == 2) ? sz : sw;
    float inv = 1.f / fmaxf((float)(j1 - j0), 1.f);
    neigh[(long)n * 64 + lane] = s * inv;
  }
}

// ---------------- generic [M,64]@[64,64] (+bias), optional row gather ----------------
template<bool GATHER>
__global__ __launch_bounds__(256) void k_gemm64(const float* __restrict__ X, const int* __restrict__ ridx,
                         const float* __restrict__ W, const float* __restrict__ bias,
                         float* __restrict__ Y, int M){
  __shared__ float lw[4096];
  for (int i = threadIdx.x; i < 4096; i += 256) lw[i] = W[i];
  __syncthreads();
  int lane = threadIdx.x & 63, wave = threadIdx.x >> 6;
  int wgl = blockIdx.x * 4 + wave;
  int nw = gridDim.x * 4;
  for (int r = wgl; r < M; r += nw){
    long src = GATHER ? (long)ridx[r] : (long)r;
    float x = X[src * 64 + lane];
    float acc = bias ? bias[lane] : 0.f;
    #pragma unroll
    for (int k = 0; k < 64; k++) acc += __shfl(x, k, 64) * lw[k * 64 + lane];
    Y[(long)r * 64 + lane] = acc;
  }
}

// ---------------- seq_query: per-batch attention + contiguous segment sum ----------------
// hq = q@W1 + b1 + b2 hoisted out of the per-position loop (q fixed per block).
template<bool GATHER_S>
__global__ __launch_bounds__(256) void k_seqq(const float* __restrict__ sbase, const int* __restrict__ sidx,
                       const float* __restrict__ qbase, const int* __restrict__ tar,
                       const float* __restrict__ W1, const float* __restrict__ b1,
                       const float* __restrict__ W2, const float* __restrict__ b2,
                       const float* __restrict__ a, const float* __restrict__ ab,
                       float* __restrict__ out, int L){
  __shared__ float lw1[4096], lw2[4096], la[64], lb[64];
  __shared__ float red[4][64];
  int tid = threadIdx.x;
  for (int i = tid; i < 4096; i += 256){ lw1[i] = W1[i]; lw2[i] = W2[i]; }
  if (tid < 64){ la[tid] = a[tid]; lb[tid] = b1[tid] + b2[tid]; }
  __syncthreads();
  int lane = tid & 63, wave = tid >> 6;
  int b = blockIdx.x;
  float q = qbase[(long)tar[b] * 64 + lane];
  float ab0 = ab[0];
  float hq = lb[lane];
  #pragma unroll
  for (int k = 0; k < 64; k++) hq += __shfl(q, k, 64) * lw1[k * 64 + lane];
  float acc = 0.f;
  for (int tl = wave; tl < L; tl += 4){
    int t = b * L + tl;
    long srow = GATHER_S ? (long)sidx[t] : (long)t;
    float s = sbase[srow * 64 + lane];
    float h = hq;
    #pragma unroll
    for (int k = 0; k < 64; k++) h += __shfl(s, k, 64) * lw2[k * 64 + lane];
    float sg = sigmf(h);
    float w = wred(sg * la[lane]) + ab0;
    acc += w * s;
  }
  red[wave][lane] = acc;
  __syncthreads();
  if (tid < 64)
    out[(long)b * 64 + tid] = red[0][tid] + red[1][tid] + red[2][tid] + red[3][tid];
}

// ---------------- per-batch mean pools (two sources, same indices) ----------------
__global__ __launch_bounds__(256) void k_pool(const float* __restrict__ neigh, const float* __restrict__ poi,
                       const int* __restrict__ sidx, float* __restrict__ p1,
                       float* __restrict__ p2, int L){
  __shared__ float r1[4][64], r2[4][64];
  int tid = threadIdx.x, lane = tid & 63, wave = tid >> 6, b = blockIdx.x;
  float a1 = 0.f, a2 = 0.f;
  for (int tl = wave; tl < L; tl += 4){
    long idx = sidx[b * L + tl];
    a1 += neigh[idx * 64 + lane];
    a2 += poi[idx * 64 + lane];
  }
  r1[wave][lane] = a1; r2[wave][lane] = a2;
  __syncthreads();
  float inv = 1.f / (float)L;
  if (tid < 64){
    p1[(long)b * 64 + tid] = (r1[0][tid] + r1[1][tid] + r1[2][tid] + r1[3][tid]) * inv;
    p2[(long)b * 64 + tid] = (r2[0][tid] + r2[1][tid] + r2[2][tid] + r2[3][tid]) * inv;
  }
}

// ---------------- GGC message scatter over T session edges ----------------
__global__ void k_edge_scatter(const int* __restrict__ e0, const int* __restrict__ e1,
                               const float* __restrict__ hw, float* __restrict__ m, int T){
  long gid = (long)blockIdx.x * blockDim.x + threadIdx.x;
  if (gid >= (long)T * 64) return;
  int e = (int)(gid >> 6), c = (int)(gid & 63);
  atomicAdd(&m[(long)e1[e] * 64 + c], hw[(long)e0[e] * 64 + c]);
}

// ---------------- GRU split, spill-free: gi = m @ wih^T + bih ----------------
__global__ __launch_bounds__(256) void k_gi(const float* __restrict__ m,
                     const float* __restrict__ wih, const float* __restrict__ bih,
                     float* __restrict__ gi, int T){
  __shared__ float lw[64 * 193];
  __shared__ float lb[192];
  int tid = threadIdx.x, lane = tid & 63, wave = tid >> 6;
  if (tid < 192) lb[tid] = bih[tid];
  for (int idx = tid; idx < 192 * 64; idx += 256){
    int j = idx >> 6, k = idx & 63;
    lw[k * 193 + j] = wih[idx];          // transposed + padded: conflict-free both ways
  }
  __syncthreads();
  int r0 = blockIdx.x * 4 + wave, nw = gridDim.x * 4;
  for (int t = r0; t < T; t += nw){
    float x = m[(long)t * 64 + lane];
    float a0 = lb[lane], a1 = lb[64 + lane], a2 = lb[128 + lane];
    #pragma unroll
    for (int k = 0; k < 64; k++){
      float xk = __shfl(x, k, 64);
      a0 += xk * lw[k * 193 + lane];
      a1 += xk * lw[k * 193 + 64 + lane];
      a2 += xk * lw[k * 193 + 128 + lane];
    }
    gi[(long)t * 192 + lane] = a0;
    gi[(long)t * 192 + 64 + lane] = a1;
    gi[(long)t * 192 + 128 + lane] = a2;
  }
}

// ---------------- GRU part 2: gh on the fly + fused gate math ----------------
__global__ __launch_bounds__(256) void k_gru2(const float* __restrict__ gi,
                       const float* __restrict__ poi, const int* __restrict__ sidx,
                       const float* __restrict__ whh, const float* __restrict__ bhh,
                       float* __restrict__ out, int T){
  __shared__ float lw[64 * 193];
  __shared__ float lb[192];
  int tid = threadIdx.x, lane = tid & 63, wave = tid >> 6;
  if (tid < 192) lb[tid] = bhh[tid];
  for (int idx = tid; idx < 192 * 64; idx += 256){
    int j = idx >> 6, k = idx & 63;
    lw[k * 193 + j] = whh[idx];
  }
  __syncthreads();
  int r0 = blockIdx.x * 4 + wave, nw = gridDim.x * 4;
  for (int t = r0; t < T; t += nw){
    float h = poi[(long)sidx[t] * 64 + lane];
    float b0 = lb[lane], b1 = lb[64 + lane], b2 = lb[128 + lane];
    #pragma unroll
    for (int k = 0; k < 64; k++){
      float hk = __shfl(h, k, 64);
      b0 += hk * lw[k * 193 + lane];
      b1 += hk * lw[k * 193 + 64 + lane];
      b2 += hk * lw[k * 193 + 128 + lane];
    }
    float r = sigmf(gi[(long)t * 192 + lane] + b0);
    float z = sigmf(gi[(long)t * 192 + 64 + lane] + b1);
    float n = tanhf(gi[(long)t * 192 + 128 + lane] + r * b2);   // n = tanh(i_n + r*h_n)
    float nh = (1.f - z) * n + z * h;
    out[(long)t * 64 + lane] = leakyf(nh);
  }
}

// ---------------- final head: con_loss, MLP logits, passthrough outputs ----------------
__global__ __launch_bounds__(64) void k_final(
    const float* __restrict__ poi, const float* __restrict__ gf,
    const int* __restrict__ tar,
    const float* __restrict__ geo_enc, const float* __restrict__ sess_enc,
    const float* __restrict__ gpool, const float* __restrict__ spool,
    const float* __restrict__ mW1, const float* __restrict__ mb1,
    const float* __restrict__ mW2, const float* __restrict__ mb2,
    const float* __restrict__ y, float* __restrict__ out, int B){
  int b = blockIdx.x, c = threadIdx.x;
  long tp = tar[b];
  long offT = 3L * B, offG = 3L * B + (long)B * 64;
  long offGP = 3L * B + 2L * B * 64, offSP = 3L * B + 3L * B * 64;
  float f0 = poi[tp * 64 + c];
  float f1 = gf[tp * 64 + c];
  float f2 = out[offSP + (long)b * 64 + c];   // sess_enc_p (already written)
  float f3 = out[offGP + (long)b * 64 + c];   // geo_enc_p
  float ge = geo_enc[(long)b * 64 + c], se = sess_enc[(long)b * 64 + c];
  float gp = gpool[(long)b * 64 + c], sp = spool[(long)b * 64 + c];
  float d1 = wred(ge * sp);
  float d2 = wred(ge * gp);
  float d3 = wred(se * gp);
  float d4 = wred(se * sp);
  float con = softplusf(d1 - d2) + softplusf(d3 - d4);
  float acc = mb1[c];
  #pragma unroll
  for (int k = 0; k < 64; k++){
    acc += __shfl(f0, k, 64) * mW1[k * 64 + c];
    acc += __shfl(f1, k, 64) * mW1[(64 + k) * 64 + c];
    acc += __shfl(f2, k, 64) * mW1[(128 + k) * 64 + c];
    acc += __shfl(f3, k, 64) * mW1[(192 + k) * 64 + c];
  }
  float hid = leakyf(acc);
  float lsum = wred(hid * mW2[c]);
  if (c == 0){
    out[b] = lsum + mb2[0];
    out[B + b] = con;
    out[2L * B + b] = y[b];
  }
  out[offT + (long)b * 64 + c] = f0;
  out[offG + (long)b * 64 + c] = f1;
}

extern "C" void kernel_launch(void* const* d_in, const int* in_sizes, int n_in,
                              void* d_out, int out_size, void* d_ws, size_t ws_size,
                              hipStream_t stream){
  const int*   sess_idx = (const int*)d_in[0];
  const int*   edges    = (const int*)d_in[1];
  const int*   tar_poi  = (const int*)d_in[3];
  const float* y        = (const float*)d_in[4];
  const int*   eidx     = (const int*)d_in[5];
  const float* dist     = (const float*)d_in[6];
  const float* poi      = (const float*)d_in[7];
  const float* geoW0    = (const float*)d_in[8];
  const float* geoW1    = (const float*)d_in[9];
  const float* ggcW     = (const float*)d_in[10];
  const float* wih      = (const float*)d_in[11];
  const float* whh      = (const float*)d_in[12];
  const float* bih      = (const float*)d_in[13];
  const float* bhh      = (const float*)d_in[14];
  const float* geoqW1   = (const float*)d_in[15];
  const float* geoqb1   = (const float*)d_in[16];
  const float* geoqW2   = (const float*)d_in[17];
  const float* geoqb2   = (const float*)d_in[18];
  const float* geoqa    = (const float*)d_in[19];
  const float* geoqab   = (const float*)d_in[20];
  const float* sessqW1  = (const float*)d_in[21];
  const float* sessqb1  = (const float*)d_in[22];
  const float* sessqW2  = (const float*)d_in[23];
  const float* sessqb2  = (const float*)d_in[24];
  const float* sessqa   = (const float*)d_in[25];
  const float* sessqab  = (const float*)d_in[26];
  const float* geo_proj = (const float*)d_in[27];
  const float* sess_proj= (const float*)d_in[28];
  const float* mW1      = (const float*)d_in[29];
  const float* mb1      = (const float*)d_in[30];
  const float* mW2      = (const float*)d_in[31];
  const float* mb2      = (const float*)d_in[32];

  const int T = in_sizes[0];
  const int B = in_sizes[3];
  const int E = in_sizes[5] / 2;
  const int N = in_sizes[7] / 64;
  const int G = in_sizes[8] / 4096;
  const int L = T / B;
  const int* erow = eidx;
  const int* ecol = eidx + E;
  const int* e0 = edges;
  const int* e1 = edges + T;

  // workspace carve-out (256B aligned).
  // gi (T*192 floats = 25.2MB) aliases gf0+csr_cv (26MB, dead post-GCN).
  // poolbuf serves as neigh (pooling) then mbuf (GGC); sessh aliases hw
  // (hw dead after k_edge_scatter, sessh written later by k_gru2).
  // rank_r/rank_c (13.2MB) alias poolbuf+hw span (21.2MB), dead after fill.
  // Total ≈ 68 MB.
  char* w = (char*)d_ws;
  size_t off = 0;
  auto nxt = [&](size_t bytes)->void*{
    void* p = w + off; off = (off + bytes + 255) & ~(size_t)255; return p;
  };
  int*   deg_row = (int*)  nxt((size_t)N * 4);
  int*   deg_col = (int*)  nxt((size_t)N * 4);
  int*   offs_r  = (int*)  nxt((size_t)(N + 1) * 4);
  int*   offs_c  = (int*)  nxt((size_t)(N + 1) * 4);
  float* dinv    = (float*)nxt((size_t)N * 4);
  float* gf1     = (float*)nxt((size_t)N * 256);        // final geo_feat lands here
  float* geo_enc = (float*)nxt((size_t)B * 256);
  float* sess_enc= (float*)nxt((size_t)B * 256);
  float* p1      = (float*)nxt((size_t)B * 256);
  float* p2      = (float*)nxt((size_t)B * 256);
  float* gpool   = (float*)nxt((size_t)B * 256);
  float* spool   = (float*)nxt((size_t)B * 256);
  float* gf0     = (float*)nxt((size_t)N * 256);        // ┐
  int2*  csr_cv  = (int2*) nxt((size_t)E * 8);          // ┘ gi aliases this span (26MB>=25.2MB)
  int*   csr_row = (int*)  nxt((size_t)E * 4);
  float* poolbuf = (float*)nxt((size_t)N * 256);        // neigh, then mbuf (T*256 <= N*256)
  float* hw      = (float*)nxt((size_t)T * 256);        // then sessh
  float* gi      = gf0;
  float* neigh   = poolbuf;
  float* mbuf    = poolbuf;
  float* sessh   = hw;
  int*   rank_r  = (int*)poolbuf;                       // spans poolbuf (12.8MB)…
  int*   rank_c  = rank_r + E;                          // …into hw; dead after k_fill2
  float* outf    = (float*)d_out;

  const long offGP = 3L * B + 2L * B * 64;
  const long offSP = 3L * B + 3L * B * 64;

  // 1. degrees (+rank capture) -> offsets (+dinv) -> atomic-free CSR fill
  hipMemsetAsync(deg_row, 0, (size_t)N * 4, stream);
  hipMemsetAsync(deg_col, 0, (size_t)N * 4, stream);
  k_deg2<<<CDIV(E,256),256,0,stream>>>(erow, ecol, deg_row, deg_col, rank_r, rank_c, E);
  k_scan2<<<2,1024,0,stream>>>(deg_row, offs_r, deg_col, offs_c, dinv, N);
  k_fill2<<<CDIV(E,256),256,0,stream>>>(erow, ecol, dist, dinv,
                                        offs_r, rank_r, csr_cv,
                                        offs_c, rank_c, csr_row, E);

  // 2. Geo-GCN layers, gather form (ping-pong so final layer lands in gf1)
  const float* cur = poi;
  float* nextb = (G & 1) ? gf1 : gf0;
  for (int g = 0; g < G; g++){
    k_gcn2<<<1024,512,0,stream>>>(offs_r, csr_cv, cur,
                                  geoW0 + (size_t)g * 4096, geoW1 + (size_t)g * 4096,
                                  nextb, N);
    cur = nextb;
    nextb = (nextb == gf0) ? gf1 : gf0;
  }
  const float* gf = cur;   // == gf1

  // 3. seq_query (geo) -> geo_enc ; projection -> out geo_enc_p
  k_seqq<true><<<B,256,0,stream>>>(gf, sess_idx, gf, tar_poi,
                                   geoqW1, geoqb1, geoqW2, geoqb2, geoqa, geoqab,
                                   geo_enc, L);
  k_gemm64<false><<<CDIV(B,4),256,0,stream>>>(geo_enc, nullptr, geo_proj, nullptr,
                                              outf + offGP, B);

  // 4. neighbor pooling, gather form (mean fused via offsets)
  k_pool_gather<<<2048,256,0,stream>>>(offs_c, csr_row, poi, neigh, N);
  k_pool<<<B,256,0,stream>>>(neigh, poi, sess_idx, p1, p2, L);
  k_gemm64<false><<<CDIV(B,4),256,0,stream>>>(p1, nullptr, geo_proj, nullptr, gpool, B);
  k_gemm64<false><<<CDIV(B,4),256,0,stream>>>(p2, nullptr, sess_proj, nullptr, spool, B);

  // 5. GatedGraphConv + GRU (poolbuf becomes mbuf; gi aliases gf0+csr_cv)
  k_gemm64<true><<<2048,256,0,stream>>>(poi, sess_idx, ggcW, nullptr, hw, T);
  hipMemsetAsync(mbuf, 0, (size_t)T * 256, stream);
  k_edge_scatter<<<(int)CDIV((long)T*64,256),256,0,stream>>>(e0, e1, hw, mbuf, T);
  k_gi<<<1024,256,0,stream>>>(mbuf, wih, bih, gi, T);
  k_gru2<<<1024,256,0,stream>>>(gi, poi, sess_idx, whh, bhh, sessh, T);

  // 6. seq_query (sess) -> sess_enc ; projection -> out sess_enc_p
  k_seqq<false><<<B,256,0,stream>>>(sessh, nullptr, poi, tar_poi,
                                    sessqW1, sessqb1, sessqW2, sessqb2, sessqa, sessqab,
                                    sess_enc, L);
  k_gemm64<false><<<CDIV(B,4),256,0,stream>>>(sess_enc, nullptr, sess_proj, nullptr,
                                              outf + offSP, B);

  // 7. final head
  k_final<<<B,64,0,stream>>>(poi, gf, tar_poi, geo_enc, sess_enc, gpool, spool,
                             mW1, mb1, mW2, mb2, y, outf, B);
}